// Round 1
// baseline (2282.666 us; speedup 1.0000x reference)
//
#include <hip/hip_runtime.h>
#include <hip/hip_bf16.h>

// ---------------------------------------------------------------------------
// ROLAND-style GNN forward:
//   h = relu(x@Wpre1+b); h = relu(h@Wpre2+b)
//   h = relu(GCNConv(h, Wc1, bc1)); emb0 = [h,prev0]@Wm1+bm1
//   h = relu(GCNConv(emb0, Wc2, bc2)); emb1 = [h,prev1]@Wm2+bm2
//   pred[l] = sum((emb1[s]*emb1[d]) @ Wpost + bpost)
// All fp32. Round 0: correctness-first.
// ---------------------------------------------------------------------------

// ---------------- generic tiled GEMM: C = [C +] A(MxK) * B(KxN) [+ bias] ----
// A row-major [M,K], B row-major [K,N], C row-major [M,N]. N%64==0, K%16==0.
template <bool RELU, bool ACCUM>
__global__ __launch_bounds__(256) void gemm_k(const float* __restrict__ A,
                                              const float* __restrict__ B,
                                              const float* __restrict__ bias,
                                              float* __restrict__ C,
                                              int M, int N, int K) {
    __shared__ float As[16][65];
    __shared__ float Bs[16][65];
    const int bm = blockIdx.y * 64;
    const int bn = blockIdx.x * 64;
    const int tid = threadIdx.x;
    const int tr = tid >> 4;   // 0..15
    const int tc = tid & 15;   // 0..15
    float acc[4][4] = {};
    for (int k0 = 0; k0 < K; k0 += 16) {
#pragma unroll
        for (int i = 0; i < 4; ++i) {          // A tile 64x16
            int idx = tid + i * 256;
            int m = idx >> 4, k = idx & 15;
            int gm = bm + m;
            As[k][m] = (gm < M) ? A[(size_t)gm * K + k0 + k] : 0.f;
        }
#pragma unroll
        for (int i = 0; i < 4; ++i) {          // B tile 16x64
            int idx = tid + i * 256;
            int k = idx >> 6, n = idx & 63;
            Bs[k][n] = B[(size_t)(k0 + k) * N + bn + n];
        }
        __syncthreads();
#pragma unroll
        for (int k = 0; k < 16; ++k) {
            float a[4], b[4];
#pragma unroll
            for (int i = 0; i < 4; ++i) a[i] = As[k][tr * 4 + i];
#pragma unroll
            for (int j = 0; j < 4; ++j) b[j] = Bs[k][tc * 4 + j];
#pragma unroll
            for (int i = 0; i < 4; ++i)
#pragma unroll
                for (int j = 0; j < 4; ++j) acc[i][j] += a[i] * b[j];
        }
        __syncthreads();
    }
#pragma unroll
    for (int i = 0; i < 4; ++i) {
        int gm = bm + tr * 4 + i;
        if (gm >= M) continue;
#pragma unroll
        for (int j = 0; j < 4; ++j) {
            int gn = bn + tc * 4 + j;
            float v = acc[i][j];
            if (bias) v += bias[gn];
            if (ACCUM) v += C[(size_t)gm * N + gn];
            if (RELU) v = fmaxf(v, 0.f);
            C[(size_t)gm * N + gn] = v;
        }
    }
}

// ---------------- GCN helpers ----------------------------------------------
__global__ void deg_kernel(const int* __restrict__ dst, float* __restrict__ deg, int E) {
    int e = blockIdx.x * blockDim.x + threadIdx.x;
    if (e < E) atomicAdd(&deg[dst[e]], 1.0f);
}

__global__ void dinv_kernel(float* __restrict__ deg, int N) {
    int i = blockIdx.x * blockDim.x + threadIdx.x;
    if (i < N) deg[i] = rsqrtf(deg[i] + 1.0f);   // in-place deg -> dinv
}

// agg[i,:] = hw[i,:] * dinv[i]^2   (self-loop term), float4-vectorized
__global__ void selfloop_kernel(const float* __restrict__ hw, const float* __restrict__ dinv,
                                float* __restrict__ agg, int N, int F) {
    int i = blockIdx.x * blockDim.x + threadIdx.x;   // over N*F/4
    int total = N * (F >> 2);
    if (i >= total) return;
    int node = i / (F >> 2);
    float d = dinv[node];
    float4 v = ((const float4*)hw)[i];
    float s = d * d;
    v.x *= s; v.y *= s; v.z *= s; v.w *= s;
    ((float4*)agg)[i] = v;
}

// one wave per edge: agg[dst,:] += hw[src,:] * dinv[src]*dinv[dst]
template <int F>
__global__ __launch_bounds__(256) void scatter_kernel(const int* __restrict__ src,
                                                      const int* __restrict__ dst,
                                                      const float* __restrict__ dinv,
                                                      const float* __restrict__ hw,
                                                      float* __restrict__ agg, int E) {
    int wave = threadIdx.x >> 6;
    int lane = threadIdx.x & 63;
    int e = blockIdx.x * 4 + wave;
    if (e >= E) return;
    int s = src[e], d = dst[e];
    float norm = dinv[s] * dinv[d];
    if (F == 128) {
        const float2 v = ((const float2*)(hw + (size_t)s * 128))[lane];
        float* out = agg + (size_t)d * 128 + lane * 2;
        atomicAdd(out + 0, v.x * norm);
        atomicAdd(out + 1, v.y * norm);
    } else {  // F == 64
        float v = hw[(size_t)s * 64 + lane];
        atomicAdd(agg + (size_t)d * 64 + lane, v * norm);
    }
}

// in-place: a = relu(a + bias[f])
__global__ void relu_bias_kernel(float* __restrict__ a, const float* __restrict__ bias, int N, int F) {
    int i = blockIdx.x * blockDim.x + threadIdx.x;   // over N*F/4
    int total = N * (F >> 2);
    if (i >= total) return;
    int f = (i << 2) % F;
    float4 v = ((float4*)a)[i];
    v.x = fmaxf(v.x + bias[f + 0], 0.f);
    v.y = fmaxf(v.y + bias[f + 1], 0.f);
    v.z = fmaxf(v.z + bias[f + 2], 0.f);
    v.w = fmaxf(v.w + bias[f + 3], 0.f);
    ((float4*)a)[i] = v;
}

// pred[l] = dot(emb1[s]*emb1[d], Wpost[:,0]+Wpost[:,1]) + bpost[0]+bpost[1]
__global__ __launch_bounds__(256) void decode_kernel(const float* __restrict__ emb1,
                                                     const int* __restrict__ eli,
                                                     const float* __restrict__ Wpost,
                                                     const float* __restrict__ bpost,
                                                     float* __restrict__ pred, int L) {
    int wave = threadIdx.x >> 6;
    int lane = threadIdx.x & 63;
    int l = blockIdx.x * 4 + wave;
    if (l >= L) return;
    int s = eli[l];
    int d = eli[L + l];
    float w = Wpost[lane * 2] + Wpost[lane * 2 + 1];
    float p = emb1[(size_t)s * 64 + lane] * emb1[(size_t)d * 64 + lane] * w;
#pragma unroll
    for (int off = 32; off; off >>= 1) p += __shfl_down(p, off);
    if (lane == 0) pred[l] = p + bpost[0] + bpost[1];
}

// ---------------------------------------------------------------------------
extern "C" void kernel_launch(void* const* d_in, const int* in_sizes, int n_in,
                              void* d_out, int out_size, void* d_ws, size_t ws_size,
                              hipStream_t stream) {
    const float* x     = (const float*)d_in[0];
    const float* prev0 = (const float*)d_in[1];
    const float* prev1 = (const float*)d_in[2];
    const float* Wpre1 = (const float*)d_in[3];
    const float* bpre1 = (const float*)d_in[4];
    const float* Wpre2 = (const float*)d_in[5];
    const float* bpre2 = (const float*)d_in[6];
    const float* Wc1   = (const float*)d_in[7];
    const float* bc1   = (const float*)d_in[8];
    const float* Wc2   = (const float*)d_in[9];
    const float* bc2   = (const float*)d_in[10];
    const float* Wm1   = (const float*)d_in[11];
    const float* bm1   = (const float*)d_in[12];
    const float* Wm2   = (const float*)d_in[13];
    const float* bm2   = (const float*)d_in[14];
    const float* Wpost = (const float*)d_in[15];
    const float* bpost = (const float*)d_in[16];
    const int* edge_index = (const int*)d_in[17];
    const int* eli        = (const int*)d_in[18];

    const int N = in_sizes[0] / 256;   // 50000
    const int E = in_sizes[17] / 2;    // 1.6M
    const int L = in_sizes[18] / 2;    // 200K

    const int* src = edge_index;       // row 0
    const int* dst = edge_index + E;   // row 1

    float* out  = (float*)d_out;
    float* pred = out;                 // [L]
    float* emb0 = out + L;             // [N,128]
    float* emb1 = out + L + (size_t)N * 128;  // [N,64]

    // workspace layout (floats)
    float* ws   = (float*)d_ws;
    float* h1   = ws;                        // [N,256]
    float* h2   = ws + (size_t)N * 256;      // [N,128]
    float* hw1  = ws;                        // [N,128]  (reuse h1: h1 dead)
    float* agg1 = ws + (size_t)N * 128;      // [N,128]  (reuse h1 upper half)
    float* dinv = ws + (size_t)N * 384;      // [N]
    float* hw2  = ws + (size_t)N * 256;      // [N,64]   (reuse h2)
    float* agg2 = ws + (size_t)N * 320;      // [N,64]

    const int gy = (N + 63) / 64;   // 782

    // 1) h1 = relu(x @ Wpre1 + bpre1)        [N,256]
    gemm_k<true, false><<<dim3(256 / 64, gy), 256, 0, stream>>>(x, Wpre1, bpre1, h1, N, 256, 256);
    // 2) h2 = relu(h1 @ Wpre2 + bpre2)       [N,128]
    gemm_k<true, false><<<dim3(128 / 64, gy), 256, 0, stream>>>(h1, Wpre2, bpre2, h2, N, 128, 256);
    // 3) hw1 = h2 @ Wc1 (no bias)            [N,128]
    gemm_k<false, false><<<dim3(128 / 64, gy), 256, 0, stream>>>(h2, Wc1, nullptr, hw1, N, 128, 128);

    // 4) degree -> dinv
    hipMemsetAsync(dinv, 0, (size_t)N * sizeof(float), stream);
    deg_kernel<<<(E + 255) / 256, 256, 0, stream>>>(dst, dinv, E);
    dinv_kernel<<<(N + 255) / 256, 256, 0, stream>>>(dinv, N);

    // 5) agg1 = hw1 * dinv^2 ; scatter edges; relu(+bc1)
    {
        int tot = N * (128 / 4);
        selfloop_kernel<<<(tot + 255) / 256, 256, 0, stream>>>(hw1, dinv, agg1, N, 128);
        scatter_kernel<128><<<(E + 3) / 4, 256, 0, stream>>>(src, dst, dinv, hw1, agg1, E);
        relu_bias_kernel<<<(tot + 255) / 256, 256, 0, stream>>>(agg1, bc1, N, 128);
    }

    // 6) emb0 = agg1 @ Wm1[:128] + bm1 ; emb0 += prev0 @ Wm1[128:]
    gemm_k<false, false><<<dim3(2, gy), 256, 0, stream>>>(agg1, Wm1, bm1, emb0, N, 128, 128);
    gemm_k<false, true><<<dim3(2, gy), 256, 0, stream>>>(prev0, Wm1 + 128 * 128, nullptr, emb0, N, 128, 128);

    // 7) hw2 = emb0 @ Wc2                     [N,64]
    gemm_k<false, false><<<dim3(1, gy), 256, 0, stream>>>(emb0, Wc2, nullptr, hw2, N, 64, 128);

    // 8) conv2 aggregation
    {
        int tot = N * (64 / 4);
        selfloop_kernel<<<(tot + 255) / 256, 256, 0, stream>>>(hw2, dinv, agg2, N, 64);
        scatter_kernel<64><<<(E + 3) / 4, 256, 0, stream>>>(src, dst, dinv, hw2, agg2, E);
        relu_bias_kernel<<<(tot + 255) / 256, 256, 0, stream>>>(agg2, bc2, N, 64);
    }

    // 9) emb1 = agg2 @ Wm2[:64] + bm2 ; emb1 += prev1 @ Wm2[64:]
    gemm_k<false, false><<<dim3(1, gy), 256, 0, stream>>>(agg2, Wm2, bm2, emb1, N, 64, 64);
    gemm_k<false, true><<<dim3(1, gy), 256, 0, stream>>>(prev1, Wm2 + 64 * 64, nullptr, emb1, N, 64, 64);

    // 10) decode
    decode_kernel<<<(L + 3) / 4, 256, 0, stream>>>(emb1, eli, Wpost, bpost, pred, L);
}

// Round 2
// 1098.585 us; speedup vs baseline: 2.0778x; 2.0778x over previous
//
#include <hip/hip_runtime.h>
#include <hip/hip_bf16.h>

// ---------------------------------------------------------------------------
// ROLAND-style GNN forward. Round 1: CSR gather instead of atomic scatter.
//   hws = (h @ Wc) * dinv[row]                     (GEMM epilogue scale)
//   agg[d] = relu(dinv[d]*(hws[d] + sum_{s in in(d)} hws[s]) + bias)
// ---------------------------------------------------------------------------

// ---------------- generic tiled GEMM: C = [C +] A(MxK)*B(KxN) [*scale][+bias]
template <bool RELU, bool ACCUM, bool SCALE>
__global__ __launch_bounds__(256) void gemm_k(const float* __restrict__ A,
                                              const float* __restrict__ B,
                                              const float* __restrict__ bias,
                                              const float* __restrict__ rowscale,
                                              float* __restrict__ C,
                                              int M, int N, int K) {
    __shared__ float As[16][65];
    __shared__ float Bs[16][65];
    const int bm = blockIdx.y * 64;
    const int bn = blockIdx.x * 64;
    const int tid = threadIdx.x;
    const int tr = tid >> 4;   // 0..15
    const int tc = tid & 15;   // 0..15
    float acc[4][4] = {};
    for (int k0 = 0; k0 < K; k0 += 16) {
#pragma unroll
        for (int i = 0; i < 4; ++i) {          // A tile 64x16
            int idx = tid + i * 256;
            int m = idx >> 4, k = idx & 15;
            int gm = bm + m;
            As[k][m] = (gm < M) ? A[(size_t)gm * K + k0 + k] : 0.f;
        }
#pragma unroll
        for (int i = 0; i < 4; ++i) {          // B tile 16x64
            int idx = tid + i * 256;
            int k = idx >> 6, n = idx & 63;
            Bs[k][n] = B[(size_t)(k0 + k) * N + bn + n];
        }
        __syncthreads();
#pragma unroll
        for (int k = 0; k < 16; ++k) {
            float a[4], b[4];
#pragma unroll
            for (int i = 0; i < 4; ++i) a[i] = As[k][tr * 4 + i];
#pragma unroll
            for (int j = 0; j < 4; ++j) b[j] = Bs[k][tc * 4 + j];
#pragma unroll
            for (int i = 0; i < 4; ++i)
#pragma unroll
                for (int j = 0; j < 4; ++j) acc[i][j] += a[i] * b[j];
        }
        __syncthreads();
    }
#pragma unroll
    for (int i = 0; i < 4; ++i) {
        int gm = bm + tr * 4 + i;
        if (gm >= M) continue;
        float sc = SCALE ? rowscale[gm] : 1.f;
#pragma unroll
        for (int j = 0; j < 4; ++j) {
            int gn = bn + tc * 4 + j;
            float v = acc[i][j];
            if (SCALE) v *= sc;
            if (bias) v += bias[gn];
            if (ACCUM) v += C[(size_t)gm * N + gn];
            if (RELU) v = fmaxf(v, 0.f);
            C[(size_t)gm * N + gn] = v;
        }
    }
}

// ---------------- degree / dinv ---------------------------------------------
__global__ void degf_kernel(const int* __restrict__ dst, float* __restrict__ deg, int E) {
    int e = blockIdx.x * blockDim.x + threadIdx.x;
    if (e < E) atomicAdd(&deg[dst[e]], 1.0f);
}

__global__ void dinv_kernel(float* __restrict__ deg, int N) {
    int i = blockIdx.x * blockDim.x + threadIdx.x;
    if (i < N) deg[i] = rsqrtf(deg[i] + 1.0f);   // in-place deg -> dinv
}

// ---------------- CSR build -------------------------------------------------
__global__ void hist_kernel(const int* __restrict__ dst, int* __restrict__ hist, int E) {
    int e = blockIdx.x * blockDim.x + threadIdx.x;
    if (e < E) atomicAdd(&hist[dst[e]], 1);
}

// single block: exclusive scan of hist[N] -> rowstart[N+1]; cursor = rowstart.
// hist and cursor may alias.
__global__ __launch_bounds__(1024) void scan_kernel(const int* __restrict__ hist,
                                                    int* __restrict__ rowstart,
                                                    int* __restrict__ cursor, int N) {
    __shared__ int sums[1024];
    const int tid = threadIdx.x;
    const int per = (N + 1023) / 1024;
    const int beg = tid * per;
    const int end = min(beg + per, N);
    int s = 0;
    for (int i = beg; i < end; ++i) s += hist[i];
    sums[tid] = s;
    __syncthreads();
    for (int off = 1; off < 1024; off <<= 1) {
        int v = (tid >= off) ? sums[tid - off] : 0;
        __syncthreads();
        sums[tid] += v;
        __syncthreads();
    }
    int run = tid ? sums[tid - 1] : 0;
    for (int i = beg; i < end; ++i) {
        int h = hist[i];           // read before cursor write (may alias)
        rowstart[i] = run;
        cursor[i] = run;
        run += h;
    }
    if (tid == 1023) rowstart[N] = sums[1023];
}

__global__ void fill_kernel(const int* __restrict__ src, const int* __restrict__ dst,
                            int* __restrict__ cursor, int* __restrict__ col, int E) {
    int e = blockIdx.x * blockDim.x + threadIdx.x;
    if (e >= E) return;
    int pos = atomicAdd(&cursor[dst[e]], 1);
    col[pos] = src[e];
}

// ---------------- CSR gather: one wave per dst node -------------------------
// agg[d,:] = relu(dinv[d]*(hws[d,:] + sum_{s} hws[s,:]) + bias)
template <int F>
__global__ __launch_bounds__(256) void gather_kernel(const int* __restrict__ rowstart,
                                                     const int* __restrict__ col,
                                                     const float* __restrict__ dinv,
                                                     const float* __restrict__ hws,
                                                     const float* __restrict__ bias,
                                                     float* __restrict__ agg, int N) {
    const int wave = threadIdx.x >> 6;
    const int lane = threadIdx.x & 63;
    const int d = blockIdx.x * 4 + wave;
    if (d >= N) return;
    const int beg = rowstart[d], end = rowstart[d + 1];
    const float dd = dinv[d];
    if (F == 128) {
        float2 acc = ((const float2*)(hws + (size_t)d * 128))[lane];
        for (int e0 = beg; e0 < end; e0 += 64) {
            int nid = (e0 + lane < end) ? col[e0 + lane] : 0;
            int cnt = min(64, end - e0);
            for (int j = 0; j < cnt; ++j) {
                int s = __shfl(nid, j);
                float2 v = ((const float2*)(hws + (size_t)s * 128))[lane];
                acc.x += v.x;
                acc.y += v.y;
            }
        }
        float2 b = ((const float2*)bias)[lane];
        acc.x = fmaxf(acc.x * dd + b.x, 0.f);
        acc.y = fmaxf(acc.y * dd + b.y, 0.f);
        ((float2*)(agg + (size_t)d * 128))[lane] = acc;
    } else {  // F == 64
        float acc = hws[(size_t)d * 64 + lane];
        for (int e0 = beg; e0 < end; e0 += 64) {
            int nid = (e0 + lane < end) ? col[e0 + lane] : 0;
            int cnt = min(64, end - e0);
            for (int j = 0; j < cnt; ++j) {
                int s = __shfl(nid, j);
                acc += hws[(size_t)s * 64 + lane];
            }
        }
        acc = fmaxf(acc * dd + bias[lane], 0.f);
        agg[(size_t)d * 64 + lane] = acc;
    }
}

// ---------------- edge decode -----------------------------------------------
__global__ __launch_bounds__(256) void decode_kernel(const float* __restrict__ emb1,
                                                     const int* __restrict__ eli,
                                                     const float* __restrict__ Wpost,
                                                     const float* __restrict__ bpost,
                                                     float* __restrict__ pred, int L) {
    const int wave = threadIdx.x >> 6;
    const int lane = threadIdx.x & 63;
    const int l = blockIdx.x * 4 + wave;
    if (l >= L) return;
    int s = eli[l];
    int d = eli[L + l];
    float w = Wpost[lane * 2] + Wpost[lane * 2 + 1];
    float p = emb1[(size_t)s * 64 + lane] * emb1[(size_t)d * 64 + lane] * w;
#pragma unroll
    for (int off = 32; off; off >>= 1) p += __shfl_down(p, off);
    if (lane == 0) pred[l] = p + bpost[0] + bpost[1];
}

// ---------------------------------------------------------------------------
extern "C" void kernel_launch(void* const* d_in, const int* in_sizes, int n_in,
                              void* d_out, int out_size, void* d_ws, size_t ws_size,
                              hipStream_t stream) {
    const float* x     = (const float*)d_in[0];
    const float* prev0 = (const float*)d_in[1];
    const float* prev1 = (const float*)d_in[2];
    const float* Wpre1 = (const float*)d_in[3];
    const float* bpre1 = (const float*)d_in[4];
    const float* Wpre2 = (const float*)d_in[5];
    const float* bpre2 = (const float*)d_in[6];
    const float* Wc1   = (const float*)d_in[7];
    const float* bc1   = (const float*)d_in[8];
    const float* Wc2   = (const float*)d_in[9];
    const float* bc2   = (const float*)d_in[10];
    const float* Wm1   = (const float*)d_in[11];
    const float* bm1   = (const float*)d_in[12];
    const float* Wm2   = (const float*)d_in[13];
    const float* bm2   = (const float*)d_in[14];
    const float* Wpost = (const float*)d_in[15];
    const float* bpost = (const float*)d_in[16];
    const int* edge_index = (const int*)d_in[17];
    const int* eli        = (const int*)d_in[18];

    const int N = in_sizes[0] / 256;   // 50000
    const int E = in_sizes[17] / 2;    // 1.6M
    const int L = in_sizes[18] / 2;    // 200K

    const int* src = edge_index;       // row 0
    const int* dst = edge_index + E;   // row 1

    float* out  = (float*)d_out;
    float* pred = out;                        // [L]
    float* emb0 = out + L;                    // [N,128]
    float* emb1 = out + L + (size_t)N * 128;  // [N,64]

    // workspace layout (floats). Peak = N*385 floats (same as round 0).
    // Timeline:  R0 [0,128N)      : h1 lower | hws1      | agg2
    //            R1 [128N,256N)   : h1 upper | agg1
    //            R2 [256N,320N)   : h2 lower | hws2
    //            R3 [320N,384N)   : h2 upper | CSR ints (rowstart,cursor,col)
    //            R4 [384N,385N)   : dinv
    float* ws   = (float*)d_ws;
    float* h1   = ws;                        // [N,256]
    float* h2   = ws + (size_t)N * 256;      // [N,128]
    float* hws1 = ws;                        // [N,128]
    float* agg1 = ws + (size_t)N * 128;      // [N,128]
    float* hws2 = ws + (size_t)N * 256;      // [N,64]
    float* agg2 = ws;                        // [N,64]
    float* dinv = ws + (size_t)N * 384;      // [N]
    int* csr      = (int*)(ws + (size_t)N * 320);  // 64N ints available
    int* rowstart = csr;                     // [N+1]
    int* cursor   = csr + (N + 1);           // [N]
    int* col      = csr + (2 * N + 1);       // [E]

    const int gy = (N + 63) / 64;   // 782

    // 0) degree -> dinv (float histogram in dinv buffer)
    hipMemsetAsync(dinv, 0, (size_t)N * sizeof(float), stream);
    degf_kernel<<<(E + 255) / 256, 256, 0, stream>>>(dst, dinv, E);
    dinv_kernel<<<(N + 255) / 256, 256, 0, stream>>>(dinv, N);

    // 1) h1 = relu(x @ Wpre1 + bpre1)        [N,256]
    gemm_k<true, false, false><<<dim3(4, gy), 256, 0, stream>>>(x, Wpre1, bpre1, nullptr, h1, N, 256, 256);
    // 2) h2 = relu(h1 @ Wpre2 + bpre2)       [N,128]
    gemm_k<true, false, false><<<dim3(2, gy), 256, 0, stream>>>(h1, Wpre2, bpre2, nullptr, h2, N, 128, 256);
    // 3) hws1 = (h2 @ Wc1) * dinv[row]       [N,128]   (h1 dead)
    gemm_k<false, false, true><<<dim3(2, gy), 256, 0, stream>>>(h2, Wc1, nullptr, dinv, hws1, N, 128, 128);

    // 4) CSR build in R3 (h2 dead after step 3)
    hipMemsetAsync(cursor, 0, (size_t)N * sizeof(int), stream);
    hist_kernel<<<(E + 255) / 256, 256, 0, stream>>>(dst, cursor, E);
    scan_kernel<<<1, 1024, 0, stream>>>(cursor, rowstart, cursor, N);
    fill_kernel<<<(E + 255) / 256, 256, 0, stream>>>(src, dst, cursor, col, E);

    // 5) agg1 = relu(dinv*(hws1[d] + sum_in hws1[s]) + bc1)
    gather_kernel<128><<<(N + 3) / 4, 256, 0, stream>>>(rowstart, col, dinv, hws1, bc1, agg1, N);

    // 6) emb0 = agg1 @ Wm1[:128] + bm1 ; emb0 += prev0 @ Wm1[128:]
    gemm_k<false, false, false><<<dim3(2, gy), 256, 0, stream>>>(agg1, Wm1, bm1, nullptr, emb0, N, 128, 128);
    gemm_k<false, true, false><<<dim3(2, gy), 256, 0, stream>>>(prev0, Wm1 + 128 * 128, nullptr, nullptr, emb0, N, 128, 128);

    // 7) hws2 = (emb0 @ Wc2) * dinv[row]     [N,64]
    gemm_k<false, false, true><<<dim3(1, gy), 256, 0, stream>>>(emb0, Wc2, nullptr, dinv, hws2, N, 64, 128);

    // 8) agg2 = relu(dinv*(hws2[d] + sum_in hws2[s]) + bc2)   (hws1 dead -> R0)
    gather_kernel<64><<<(N + 3) / 4, 256, 0, stream>>>(rowstart, col, dinv, hws2, bc2, agg2, N);

    // 9) emb1 = agg2 @ Wm2[:64] + bm2 ; emb1 += prev1 @ Wm2[64:]
    gemm_k<false, false, false><<<dim3(1, gy), 256, 0, stream>>>(agg2, Wm2, bm2, nullptr, emb1, N, 64, 64);
    gemm_k<false, true, false><<<dim3(1, gy), 256, 0, stream>>>(prev1, Wm2 + 64 * 64, nullptr, nullptr, emb1, N, 64, 64);

    // 10) decode
    decode_kernel<<<(L + 3) / 4, 256, 0, stream>>>(emb1, eli, Wpost, bpost, pred, L);
}

// Round 4
// 855.532 us; speedup vs baseline: 2.6681x; 1.2841x over previous
//
#include <hip/hip_runtime.h>
#include <hip/hip_bf16.h>

// ---------------------------------------------------------------------------
// ROLAND-style GNN forward. Round 3: fix workspace overlap that NaN'd round 2.
// All GEMMs via bf16 MFMA with hi/lo split-precision (3-pass) emulation of
// fp32; CSR gather for GCN aggregation.
// h1l scratch lives in d_out's emb0 region (dead until step 5).
// ---------------------------------------------------------------------------

typedef unsigned short ushort_t;
typedef __attribute__((ext_vector_type(8))) short s8v;   // 8 bf16 (4 VGPRs)
typedef __attribute__((ext_vector_type(4))) float f4;    // MFMA accumulator

// split fp32 into two bf16 (RNE): v ~= hi + lo
__device__ __forceinline__ void bsplit(float v, ushort_t& hi, ushort_t& lo) {
    unsigned u = __float_as_uint(v);
    unsigned rh = u + 0x7FFFu + ((u >> 16) & 1u);
    hi = (ushort_t)(rh >> 16);
    float fh = __uint_as_float((unsigned)hi << 16);
    float d = v - fh;
    unsigned u2 = __float_as_uint(d);
    unsigned rl = u2 + 0x7FFFu + ((u2 >> 16) & 1u);
    lo = (ushort_t)(rl >> 16);
}

// ---------------- MFMA GEMM -------------------------------------------------
// C[M,Nout] = epilogue( A[M,K1] (++ A2[M,K2]) @ W[K,Nout] )
// Wth/Wtl: [Nout][KW] bf16 (transposed+split). A staged 128x64 fp32->hi/lo
// bf16 in LDS, chunk-XOR swizzle. 256 thr = 4 waves (2x2); BM=128, BN=NT*32.
template <int NT, bool RELU, bool SCALE, bool DUAL, bool AHILO, bool OUTHILO>
__global__ __launch_bounds__(256) void gemm_mfma(
    const float* __restrict__ A1f, const ushort_t* __restrict__ A1h,
    const ushort_t* __restrict__ A1l, int K1,
    const float* __restrict__ A2f, int K2,
    const ushort_t* __restrict__ Wth, const ushort_t* __restrict__ Wtl,
    const float* __restrict__ bias, const float* __restrict__ rowscale,
    float* __restrict__ Cf, ushort_t* __restrict__ Ch, ushort_t* __restrict__ Cl,
    int M, int Nout)
{
    __shared__ ushort_t Ah[128 * 64];
    __shared__ ushort_t Al[128 * 64];
    const int tid  = threadIdx.x;
    const int lane = tid & 63;
    const int w    = tid >> 6;
    const int wr   = w >> 1, wc = w & 1;
    const int bm   = blockIdx.y * 128;
    const int bn   = blockIdx.x * (NT * 32);
    const int KW   = K1 + (DUAL ? K2 : 0);

    f4 acc[4][NT];
    const f4 zero = {0.f, 0.f, 0.f, 0.f};
#pragma unroll
    for (int mi = 0; mi < 4; ++mi)
#pragma unroll
        for (int ni = 0; ni < NT; ++ni) acc[mi][ni] = zero;

    const int sr = tid >> 1;                 // staging row 0..127
    const int sh = tid & 1;                  // staging half
    const int gr = min(bm + sr, M - 1);      // clamped global row

    for (int kt = 0; kt < KW; kt += 64) {
        // ---- stage A tile (128x64) -> hi/lo bf16 LDS, swizzled chunks ----
        {
            const bool ph2 = DUAL && (kt >= K1);
            const float* Af = ph2 ? A2f : A1f;
            const int kb = ph2 ? (kt - K1) : kt;
            const int Ks = ph2 ? K2 : K1;
#pragma unroll
            for (int j = 0; j < 4; ++j) {
                const int c = sh * 4 + j;          // logical 8-elem chunk
                const int p = c ^ (sr & 7);        // physical chunk (swizzle)
                ushort_t hb[8], lb[8];
                if (AHILO && !ph2) {
                    *(s8v*)hb = *(const s8v*)&A1h[(size_t)gr * K1 + kb + c * 8];
                    *(s8v*)lb = *(const s8v*)&A1l[(size_t)gr * K1 + kb + c * 8];
                } else {
                    const float* srcp = &Af[(size_t)gr * Ks + kb + c * 8];
                    f4 v0 = *(const f4*)srcp;
                    f4 v1 = *(const f4*)(srcp + 4);
                    bsplit(v0.x, hb[0], lb[0]); bsplit(v0.y, hb[1], lb[1]);
                    bsplit(v0.z, hb[2], lb[2]); bsplit(v0.w, hb[3], lb[3]);
                    bsplit(v1.x, hb[4], lb[4]); bsplit(v1.y, hb[5], lb[5]);
                    bsplit(v1.z, hb[6], lb[6]); bsplit(v1.w, hb[7], lb[7]);
                }
                *(s8v*)&Ah[sr * 64 + p * 8] = *(const s8v*)hb;
                *(s8v*)&Al[sr * 64 + p * 8] = *(const s8v*)lb;
            }
        }
        __syncthreads();
        // ---- compute: 2 k-subtiles of 32 ----
#pragma unroll
        for (int ks = 0; ks < 2; ++ks) {
            s8v bh[NT], bl[NT];
#pragma unroll
            for (int ni = 0; ni < NT; ++ni) {
                const int n = bn + wc * (NT * 16) + ni * 16 + (lane & 15);
                const size_t off = (size_t)n * KW + kt + ks * 32 + (lane >> 4) * 8;
                bh[ni] = *(const s8v*)&Wth[off];
                bl[ni] = *(const s8v*)&Wtl[off];
            }
#pragma unroll
            for (int mi = 0; mi < 4; ++mi) {
                const int row = wr * 64 + mi * 16 + (lane & 15);
                const int c = ks * 4 + (lane >> 4);
                const int p = c ^ (row & 7);
                const s8v ah = *(const s8v*)&Ah[row * 64 + p * 8];
                const s8v al = *(const s8v*)&Al[row * 64 + p * 8];
#pragma unroll
                for (int ni = 0; ni < NT; ++ni) {
                    acc[mi][ni] = __builtin_amdgcn_mfma_f32_16x16x32_bf16(ah, bh[ni], acc[mi][ni], 0, 0, 0);
                    acc[mi][ni] = __builtin_amdgcn_mfma_f32_16x16x32_bf16(ah, bl[ni], acc[mi][ni], 0, 0, 0);
                    acc[mi][ni] = __builtin_amdgcn_mfma_f32_16x16x32_bf16(al, bh[ni], acc[mi][ni], 0, 0, 0);
                }
            }
        }
        __syncthreads();
    }
    // ---- epilogue: C/D layout col=lane&15, row=(lane>>4)*4+reg ----
#pragma unroll
    for (int mi = 0; mi < 4; ++mi) {
#pragma unroll
        for (int reg = 0; reg < 4; ++reg) {
            const int row = bm + wr * 64 + mi * 16 + (lane >> 4) * 4 + reg;
            if (row >= M) continue;
            const float rs = SCALE ? rowscale[row] : 1.f;
#pragma unroll
            for (int ni = 0; ni < NT; ++ni) {
                const int col = bn + wc * (NT * 16) + ni * 16 + (lane & 15);
                float v = acc[mi][ni][reg];
                if (SCALE) v *= rs;
                if (bias) v += bias[col];
                if (RELU) v = fmaxf(v, 0.f);
                if constexpr (OUTHILO) {
                    ushort_t h, l;
                    bsplit(v, h, l);
                    Ch[(size_t)row * Nout + col] = h;
                    Cl[(size_t)row * Nout + col] = l;
                } else {
                    Cf[(size_t)row * Nout + col] = v;
                }
            }
        }
    }
}

// ---------------- weight transpose + split ---------------------------------
struct WDesc { const float* W; ushort_t* h; ushort_t* l; int K; int No; };
struct WAll { WDesc d[6]; };

__global__ void wtcvt_kernel(WAll wa) {
    WDesc d = wa.d[blockIdx.y];
    int e = blockIdx.x * blockDim.x + threadIdx.x;
    if (e >= d.K * d.No) return;
    int k = e / d.No, n = e - k * d.No;
    ushort_t h, l;
    bsplit(d.W[e], h, l);
    d.h[(size_t)n * d.K + k] = h;
    d.l[(size_t)n * d.K + k] = l;
}

// ---------------- degree / dinv ---------------------------------------------
__global__ void degf_kernel(const int* __restrict__ dst, float* __restrict__ deg, int E) {
    int e = blockIdx.x * blockDim.x + threadIdx.x;
    if (e < E) atomicAdd(&deg[dst[e]], 1.0f);
}

__global__ void dinv_k(float* __restrict__ deg, int N) {
    int i = blockIdx.x * blockDim.x + threadIdx.x;
    if (i < N) deg[i] = rsqrtf(deg[i] + 1.0f);
}

// ---------------- CSR build -------------------------------------------------
__global__ void hist_kernel(const int* __restrict__ dst, int* __restrict__ hist, int E) {
    int e = blockIdx.x * blockDim.x + threadIdx.x;
    if (e < E) atomicAdd(&hist[dst[e]], 1);
}

__global__ __launch_bounds__(1024) void scan_kernel(const int* __restrict__ hist,
                                                    int* __restrict__ rowstart,
                                                    int* __restrict__ cursor, int N) {
    __shared__ int sums[1024];
    const int tid = threadIdx.x;
    const int per = (N + 1023) / 1024;
    const int beg = tid * per;
    const int end = min(beg + per, N);
    int s = 0;
    for (int i = beg; i < end; ++i) s += hist[i];
    sums[tid] = s;
    __syncthreads();
    for (int off = 1; off < 1024; off <<= 1) {
        int v = (tid >= off) ? sums[tid - off] : 0;
        __syncthreads();
        sums[tid] += v;
        __syncthreads();
    }
    int run = tid ? sums[tid - 1] : 0;
    for (int i = beg; i < end; ++i) {
        int h = hist[i];
        rowstart[i] = run;
        cursor[i] = run;
        run += h;
    }
    if (tid == 1023) rowstart[N] = sums[1023];
}

__global__ void fill_kernel(const int* __restrict__ src, const int* __restrict__ dst,
                            int* __restrict__ cursor, int* __restrict__ col, int E) {
    int e = blockIdx.x * blockDim.x + threadIdx.x;
    if (e >= E) return;
    int pos = atomicAdd(&cursor[dst[e]], 1);
    col[pos] = src[e];
}

// ---------------- CSR gather ------------------------------------------------
template <int F>
__global__ __launch_bounds__(256) void gather_kernel(const int* __restrict__ rowstart,
                                                     const int* __restrict__ col,
                                                     const float* __restrict__ dinv,
                                                     const float* __restrict__ hws,
                                                     const float* __restrict__ bias,
                                                     float* __restrict__ agg, int N) {
    const int wave = threadIdx.x >> 6;
    const int lane = threadIdx.x & 63;
    const int d = blockIdx.x * 4 + wave;
    if (d >= N) return;
    const int beg = rowstart[d], end = rowstart[d + 1];
    const float dd = dinv[d];
    if (F == 128) {
        float2 acc = ((const float2*)(hws + (size_t)d * 128))[lane];
        for (int e0 = beg; e0 < end; e0 += 64) {
            int nid = (e0 + lane < end) ? col[e0 + lane] : 0;
            int cnt = min(64, end - e0);
            for (int j = 0; j < cnt; ++j) {
                int s = __shfl(nid, j);
                float2 v = ((const float2*)(hws + (size_t)s * 128))[lane];
                acc.x += v.x;
                acc.y += v.y;
            }
        }
        float2 b = ((const float2*)bias)[lane];
        acc.x = fmaxf(acc.x * dd + b.x, 0.f);
        acc.y = fmaxf(acc.y * dd + b.y, 0.f);
        ((float2*)(agg + (size_t)d * 128))[lane] = acc;
    } else {
        float acc = hws[(size_t)d * 64 + lane];
        for (int e0 = beg; e0 < end; e0 += 64) {
            int nid = (e0 + lane < end) ? col[e0 + lane] : 0;
            int cnt = min(64, end - e0);
            for (int j = 0; j < cnt; ++j) {
                int s = __shfl(nid, j);
                acc += hws[(size_t)s * 64 + lane];
            }
        }
        acc = fmaxf(acc * dd + bias[lane], 0.f);
        agg[(size_t)d * 64 + lane] = acc;
    }
}

// ---------------- edge decode -----------------------------------------------
__global__ __launch_bounds__(256) void decode_kernel(const float* __restrict__ emb1,
                                                     const int* __restrict__ eli,
                                                     const float* __restrict__ Wpost,
                                                     const float* __restrict__ bpost,
                                                     float* __restrict__ pred, int L) {
    const int wave = threadIdx.x >> 6;
    const int lane = threadIdx.x & 63;
    const int l = blockIdx.x * 4 + wave;
    if (l >= L) return;
    int s = eli[l];
    int d = eli[L + l];
    float w = Wpost[lane * 2] + Wpost[lane * 2 + 1];
    float p = emb1[(size_t)s * 64 + lane] * emb1[(size_t)d * 64 + lane] * w;
#pragma unroll
    for (int off = 32; off; off >>= 1) p += __shfl_down(p, off);
    if (lane == 0) pred[l] = p + bpost[0] + bpost[1];
}

// ---------------------------------------------------------------------------
extern "C" void kernel_launch(void* const* d_in, const int* in_sizes, int n_in,
                              void* d_out, int out_size, void* d_ws, size_t ws_size,
                              hipStream_t stream) {
    const float* x     = (const float*)d_in[0];
    const float* prev0 = (const float*)d_in[1];
    const float* prev1 = (const float*)d_in[2];
    const float* Wpre1 = (const float*)d_in[3];
    const float* bpre1 = (const float*)d_in[4];
    const float* Wpre2 = (const float*)d_in[5];
    const float* bpre2 = (const float*)d_in[6];
    const float* Wc1   = (const float*)d_in[7];
    const float* bc1   = (const float*)d_in[8];
    const float* Wc2   = (const float*)d_in[9];
    const float* bc2   = (const float*)d_in[10];
    const float* Wm1   = (const float*)d_in[11];
    const float* bm1   = (const float*)d_in[12];
    const float* Wm2   = (const float*)d_in[13];
    const float* bm2   = (const float*)d_in[14];
    const float* Wpost = (const float*)d_in[15];
    const float* bpost = (const float*)d_in[16];
    const int* edge_index = (const int*)d_in[17];
    const int* eli        = (const int*)d_in[18];

    const int N = in_sizes[0] / 256;   // 50000
    const int E = in_sizes[17] / 2;    // 1.6M
    const int L = in_sizes[18] / 2;    // 200K

    const int* src = edge_index;
    const int* dst = edge_index + E;

    float* out  = (float*)d_out;
    float* pred = out;                        // [L]
    float* emb0 = out + L;                    // [N,128]
    float* emb1 = out + L + (size_t)N * 128;  // [N,64]

    // ---- workspace layout (float slots; peak ~294N = 59 MB) ----
    // [0,128N)    : h1h (G1->G2) | hws1 (G3->gather1) | hws2[0,64N)+agg2[64N,128N)
    // [128N,256N) : cursor (step 0 only) | h2 (G2->G3) | agg1 (gather1->G5)
    // [256N, ...) : col[E], rowstart[N+1], dinv[N], weights (aligned)
    // h1l lives in d_out's emb0 region (dead until G5): 128N floats = 256N ushorts.
    float* ws = (float*)d_ws;
    ushort_t* h1h = (ushort_t*)ws;                    // [N,256] ushorts
    ushort_t* h1l = (ushort_t*)emb0;                  // [N,256] ushorts (d_out scratch)
    float* hws1 = ws;                                 // [N,128]
    float* hws2 = ws;                                 // [N,64]
    float* agg2 = ws + (size_t)64 * N;                // [N,64]
    float* h2   = ws + (size_t)128 * N;               // [N,128]
    float* agg1 = ws + (size_t)128 * N;               // [N,128]
    int* cursor = (int*)(ws + (size_t)128 * N);       // [N] (dead before G1)

    size_t o = (size_t)256 * N;
    int* col = (int*)(ws + o);            o += (size_t)(E + 3) & ~(size_t)3;
    int* rowstart = (int*)(ws + o);       o += (size_t)(N + 4) & ~(size_t)3;
    float* dinv = ws + o;                 o += (size_t)(N + 3) & ~(size_t)3;
    ushort_t* wb = (ushort_t*)(ws + o);   // 327680 ushorts (16B-aligned)

    // weight hi/lo offsets (ushorts) within wb
    ushort_t* wpre1h = wb + 0;       ushort_t* wpre1l = wb + 65536;
    ushort_t* wpre2h = wb + 131072;  ushort_t* wpre2l = wb + 163840;
    ushort_t* wc1h   = wb + 196608;  ushort_t* wc1l   = wb + 212992;
    ushort_t* wm1h   = wb + 229376;  ushort_t* wm1l   = wb + 262144;
    ushort_t* wc2h   = wb + 294912;  ushort_t* wc2l   = wb + 303104;
    ushort_t* wm2h   = wb + 311296;  ushort_t* wm2l   = wb + 319488;

    // 0) degree -> dinv ; CSR build
    hipMemsetAsync(dinv, 0, (size_t)N * sizeof(float), stream);
    degf_kernel<<<(E + 255) / 256, 256, 0, stream>>>(dst, dinv, E);
    dinv_k<<<(N + 255) / 256, 256, 0, stream>>>(dinv, N);
    hipMemsetAsync(cursor, 0, (size_t)N * sizeof(int), stream);
    hist_kernel<<<(E + 255) / 256, 256, 0, stream>>>(dst, cursor, E);
    scan_kernel<<<1, 1024, 0, stream>>>(cursor, rowstart, cursor, N);
    fill_kernel<<<(E + 255) / 256, 256, 0, stream>>>(src, dst, cursor, col, E);

    // 0b) weights: transpose + hi/lo split
    WAll wa;
    wa.d[0] = {Wpre1, wpre1h, wpre1l, 256, 256};
    wa.d[1] = {Wpre2, wpre2h, wpre2l, 256, 128};
    wa.d[2] = {Wc1,   wc1h,   wc1l,   128, 128};
    wa.d[3] = {Wm1,   wm1h,   wm1l,   256, 128};
    wa.d[4] = {Wc2,   wc2h,   wc2l,   128, 64};
    wa.d[5] = {Wm2,   wm2h,   wm2l,   128, 64};
    wtcvt_kernel<<<dim3(256, 6), 256, 0, stream>>>(wa);

    const int gy = (N + 127) / 128;   // 391

    // 1) h1 = relu(x@Wpre1+b) -> hi/lo bf16            [N,256]
    gemm_mfma<4, true, false, false, false, true><<<dim3(2, gy), 256, 0, stream>>>(
        x, nullptr, nullptr, 256, nullptr, 0, wpre1h, wpre1l, bpre1, nullptr,
        nullptr, h1h, h1l, N, 256);
    // 2) h2 = relu(h1@Wpre2+b)                         [N,128]
    gemm_mfma<4, true, false, false, true, false><<<dim3(1, gy), 256, 0, stream>>>(
        nullptr, h1h, h1l, 256, nullptr, 0, wpre2h, wpre2l, bpre2, nullptr,
        h2, nullptr, nullptr, N, 128);
    // 3) hws1 = (h2@Wc1)*dinv[row]                     [N,128]  (h1 dead)
    gemm_mfma<4, false, true, false, false, false><<<dim3(1, gy), 256, 0, stream>>>(
        h2, nullptr, nullptr, 128, nullptr, 0, wc1h, wc1l, nullptr, dinv,
        hws1, nullptr, nullptr, N, 128);
    // 4) agg1 = relu(dinv*(hws1[d]+sum hws1[s])+bc1)   (h2 dead)
    gather_kernel<128><<<(N + 3) / 4, 256, 0, stream>>>(rowstart, col, dinv, hws1, bc1, agg1, N);
    // 5) emb0 = [agg1,prev0]@Wm1+bm1  (dual-source concat GEMM)
    gemm_mfma<4, false, false, true, false, false><<<dim3(1, gy), 256, 0, stream>>>(
        agg1, nullptr, nullptr, 128, prev0, 128, wm1h, wm1l, bm1, nullptr,
        emb0, nullptr, nullptr, N, 128);
    // 6) hws2 = (emb0@Wc2)*dinv[row]                   [N,64]  (hws1 dead)
    gemm_mfma<2, false, true, false, false, false><<<dim3(1, gy), 256, 0, stream>>>(
        emb0, nullptr, nullptr, 128, nullptr, 0, wc2h, wc2l, nullptr, dinv,
        hws2, nullptr, nullptr, N, 64);
    // 7) agg2 = relu(dinv*(hws2[d]+sum hws2[s])+bc2)
    gather_kernel<64><<<(N + 3) / 4, 256, 0, stream>>>(rowstart, col, dinv, hws2, bc2, agg2, N);
    // 8) emb1 = [agg2,prev1]@Wm2+bm2
    gemm_mfma<2, false, false, true, false, false><<<dim3(1, gy), 256, 0, stream>>>(
        agg2, nullptr, nullptr, 64, prev1, 64, wm2h, wm2l, bm2, nullptr,
        emb1, nullptr, nullptr, N, 64);
    // 9) decode
    decode_kernel<<<(L + 3) / 4, 256, 0, stream>>>(emb1, eli, Wpost, bpost, pred, L);
}

// Round 5
// 540.628 us; speedup vs baseline: 4.2222x; 1.5825x over previous
//
#include <hip/hip_runtime.h>
#include <hip/hip_bf16.h>

// ---------------------------------------------------------------------------
// ROLAND-style GNN forward. Round 4: bucketed CSR build (2-level counting
// sort) replaces hist+scan+atomic-fill; degree/dinv folded into the build.
// GEMMs: bf16 MFMA hi/lo split-precision (3-pass). Aggregation: CSR gather.
// ---------------------------------------------------------------------------

typedef unsigned short ushort_t;
typedef __attribute__((ext_vector_type(8))) short s8v;   // 8 bf16 (4 VGPRs)
typedef __attribute__((ext_vector_type(4))) float f4;    // MFMA accumulator

#define BSHIFT 8                       // nodes per bucket = 256 (N<=65536)

// split fp32 into two bf16 (RNE): v ~= hi + lo
__device__ __forceinline__ void bsplit(float v, ushort_t& hi, ushort_t& lo) {
    unsigned u = __float_as_uint(v);
    unsigned rh = u + 0x7FFFu + ((u >> 16) & 1u);
    hi = (ushort_t)(rh >> 16);
    float fh = __uint_as_float((unsigned)hi << 16);
    float d = v - fh;
    unsigned u2 = __float_as_uint(d);
    unsigned rl = u2 + 0x7FFFu + ((u2 >> 16) & 1u);
    lo = (ushort_t)(rl >> 16);
}

// ---------------- MFMA GEMM -------------------------------------------------
// C[M,Nout] = epilogue( A[M,K1] (++ A2[M,K2]) @ W[K,Nout] )
// Wth/Wtl: [Nout][KW] bf16 (transposed+split). A staged 128x64 fp32->hi/lo
// bf16 in LDS, chunk-XOR swizzle. 256 thr = 4 waves (2x2); BM=128, BN=NT*32.
template <int NT, bool RELU, bool SCALE, bool DUAL, bool AHILO, bool OUTHILO>
__global__ __launch_bounds__(256) void gemm_mfma(
    const float* __restrict__ A1f, const ushort_t* __restrict__ A1h,
    const ushort_t* __restrict__ A1l, int K1,
    const float* __restrict__ A2f, int K2,
    const ushort_t* __restrict__ Wth, const ushort_t* __restrict__ Wtl,
    const float* __restrict__ bias, const float* __restrict__ rowscale,
    float* __restrict__ Cf, ushort_t* __restrict__ Ch, ushort_t* __restrict__ Cl,
    int M, int Nout)
{
    __shared__ ushort_t Ah[128 * 64];
    __shared__ ushort_t Al[128 * 64];
    const int tid  = threadIdx.x;
    const int lane = tid & 63;
    const int w    = tid >> 6;
    const int wr   = w >> 1, wc = w & 1;
    const int bm   = blockIdx.y * 128;
    const int bn   = blockIdx.x * (NT * 32);
    const int KW   = K1 + (DUAL ? K2 : 0);

    f4 acc[4][NT];
    const f4 zero = {0.f, 0.f, 0.f, 0.f};
#pragma unroll
    for (int mi = 0; mi < 4; ++mi)
#pragma unroll
        for (int ni = 0; ni < NT; ++ni) acc[mi][ni] = zero;

    const int sr = tid >> 1;                 // staging row 0..127
    const int sh = tid & 1;                  // staging half
    const int gr = min(bm + sr, M - 1);      // clamped global row

    for (int kt = 0; kt < KW; kt += 64) {
        // ---- stage A tile (128x64) -> hi/lo bf16 LDS, swizzled chunks ----
        {
            const bool ph2 = DUAL && (kt >= K1);
            const float* Af = ph2 ? A2f : A1f;
            const int kb = ph2 ? (kt - K1) : kt;
            const int Ks = ph2 ? K2 : K1;
#pragma unroll
            for (int j = 0; j < 4; ++j) {
                const int c = sh * 4 + j;          // logical 8-elem chunk
                const int p = c ^ (sr & 7);        // physical chunk (swizzle)
                ushort_t hb[8], lb[8];
                if (AHILO && !ph2) {
                    *(s8v*)hb = *(const s8v*)&A1h[(size_t)gr * K1 + kb + c * 8];
                    *(s8v*)lb = *(const s8v*)&A1l[(size_t)gr * K1 + kb + c * 8];
                } else {
                    const float* srcp = &Af[(size_t)gr * Ks + kb + c * 8];
                    f4 v0 = *(const f4*)srcp;
                    f4 v1 = *(const f4*)(srcp + 4);
                    bsplit(v0.x, hb[0], lb[0]); bsplit(v0.y, hb[1], lb[1]);
                    bsplit(v0.z, hb[2], lb[2]); bsplit(v0.w, hb[3], lb[3]);
                    bsplit(v1.x, hb[4], lb[4]); bsplit(v1.y, hb[5], lb[5]);
                    bsplit(v1.z, hb[6], lb[6]); bsplit(v1.w, hb[7], lb[7]);
                }
                *(s8v*)&Ah[sr * 64 + p * 8] = *(const s8v*)hb;
                *(s8v*)&Al[sr * 64 + p * 8] = *(const s8v*)lb;
            }
        }
        __syncthreads();
        // ---- compute: 2 k-subtiles of 32 ----
#pragma unroll
        for (int ks = 0; ks < 2; ++ks) {
            s8v bh[NT], bl[NT];
#pragma unroll
            for (int ni = 0; ni < NT; ++ni) {
                const int n = bn + wc * (NT * 16) + ni * 16 + (lane & 15);
                const size_t off = (size_t)n * KW + kt + ks * 32 + (lane >> 4) * 8;
                bh[ni] = *(const s8v*)&Wth[off];
                bl[ni] = *(const s8v*)&Wtl[off];
            }
#pragma unroll
            for (int mi = 0; mi < 4; ++mi) {
                const int row = wr * 64 + mi * 16 + (lane & 15);
                const int c = ks * 4 + (lane >> 4);
                const int p = c ^ (row & 7);
                const s8v ah = *(const s8v*)&Ah[row * 64 + p * 8];
                const s8v al = *(const s8v*)&Al[row * 64 + p * 8];
#pragma unroll
                for (int ni = 0; ni < NT; ++ni) {
                    acc[mi][ni] = __builtin_amdgcn_mfma_f32_16x16x32_bf16(ah, bh[ni], acc[mi][ni], 0, 0, 0);
                    acc[mi][ni] = __builtin_amdgcn_mfma_f32_16x16x32_bf16(ah, bl[ni], acc[mi][ni], 0, 0, 0);
                    acc[mi][ni] = __builtin_amdgcn_mfma_f32_16x16x32_bf16(al, bh[ni], acc[mi][ni], 0, 0, 0);
                }
            }
        }
        __syncthreads();
    }
    // ---- epilogue: C/D layout col=lane&15, row=(lane>>4)*4+reg ----
#pragma unroll
    for (int mi = 0; mi < 4; ++mi) {
#pragma unroll
        for (int reg = 0; reg < 4; ++reg) {
            const int row = bm + wr * 64 + mi * 16 + (lane >> 4) * 4 + reg;
            if (row >= M) continue;
            const float rs = SCALE ? rowscale[row] : 1.f;
#pragma unroll
            for (int ni = 0; ni < NT; ++ni) {
                const int col = bn + wc * (NT * 16) + ni * 16 + (lane & 15);
                float v = acc[mi][ni][reg];
                if (SCALE) v *= rs;
                if (bias) v += bias[col];
                if (RELU) v = fmaxf(v, 0.f);
                if constexpr (OUTHILO) {
                    ushort_t h, l;
                    bsplit(v, h, l);
                    Ch[(size_t)row * Nout + col] = h;
                    Cl[(size_t)row * Nout + col] = l;
                } else {
                    Cf[(size_t)row * Nout + col] = v;
                }
            }
        }
    }
}

// ---------------- weight transpose + split ---------------------------------
struct WDesc { const float* W; ushort_t* h; ushort_t* l; int K; int No; };
struct WAll { WDesc d[6]; };

__global__ void wtcvt_kernel(WAll wa) {
    WDesc d = wa.d[blockIdx.y];
    int e = blockIdx.x * blockDim.x + threadIdx.x;
    if (e >= d.K * d.No) return;
    int k = e / d.No, n = e - k * d.No;
    ushort_t h, l;
    bsplit(d.W[e], h, l);
    d.h[(size_t)n * d.K + k] = h;
    d.l[(size_t)n * d.K + k] = l;
}

// ---------------- bucketed CSR build ----------------------------------------
// A: count edges per bucket (bucket = dst >> BSHIFT, NB <= 256)
__global__ __launch_bounds__(256) void bcount_kernel(const int* __restrict__ dst,
                                                     int* __restrict__ bcount, int E, int NB) {
    __shared__ int cnt[256];
    const int t = threadIdx.x;
    if (t < NB) cnt[t] = 0;
    __syncthreads();
    for (int e = blockIdx.x * 256 + t; e < E; e += gridDim.x * 256)
        atomicAdd(&cnt[dst[e] >> BSHIFT], 1);
    __syncthreads();
    if (t < NB && cnt[t]) atomicAdd(&bcount[t], cnt[t]);
}

// B: single-block exclusive scan -> bbase[NB+1], bcursor = bbase
__global__ __launch_bounds__(256) void bscan_kernel(const int* __restrict__ bcount,
                                                    int* __restrict__ bbase,
                                                    int* __restrict__ bcursor, int NB, int E) {
    __shared__ int s[256];
    const int t = threadIdx.x;
    s[t] = (t < NB) ? bcount[t] : 0;
    __syncthreads();
    for (int off = 1; off < 256; off <<= 1) {
        int v = (t >= off) ? s[t - off] : 0;
        __syncthreads();
        s[t] += v;
        __syncthreads();
    }
    int excl = t ? s[t - 1] : 0;
    if (t < NB) { bbase[t] = excl; bcursor[t] = excl; }
    if (t == 0) bbase[NB] = E;
}

// C: partition edges into bucket regions as packed (src | dst_lo<<16).
// Each block handles an 8192-edge chunk: LDS count -> one global atomic per
// (block,bucket) range reservation -> dense packed writes.
__global__ __launch_bounds__(256) void bpart_kernel(const int* __restrict__ src,
                                                    const int* __restrict__ dst,
                                                    int* __restrict__ bcursor,
                                                    unsigned* __restrict__ packed, int E, int NB) {
    __shared__ int cnt[256];
    __shared__ int cur[256];
    const int t = threadIdx.x;
    const int beg = blockIdx.x * 8192;
    const int end = min(beg + 8192, E);
    if (t < NB) cnt[t] = 0;
    __syncthreads();
    for (int e = beg + t; e < end; e += 256) atomicAdd(&cnt[dst[e] >> BSHIFT], 1);
    __syncthreads();
    if (t < NB && cnt[t]) cur[t] = atomicAdd(&bcursor[t], cnt[t]);
    __syncthreads();
    for (int e = beg + t; e < end; e += 256) {
        int d = dst[e];
        int b = d >> BSHIFT;
        int pos = atomicAdd(&cur[b], 1);
        packed[pos] = (unsigned)src[e] | ((unsigned)(d & ((1 << BSHIFT) - 1)) << 16);
    }
}

// D: one block per bucket: per-node counts -> rowstart + dinv + ordered col.
__global__ __launch_bounds__(256) void bbuild_kernel(const int* __restrict__ bbase,
                                                     const unsigned* __restrict__ packed,
                                                     int* __restrict__ col,
                                                     int* __restrict__ rowstart,
                                                     float* __restrict__ dinv, int N, int E) {
    __shared__ int ncnt[256];
    __shared__ int s[256];
    __shared__ int ncur[256];
    const int b = blockIdx.x;
    const int t = threadIdx.x;
    const int beg = bbase[b], end = bbase[b + 1];
    const int node0 = b << BSHIFT;
    const int nInB = min(256, N - node0);
    ncnt[t] = 0;
    __syncthreads();
    for (int e = beg + t; e < end; e += 256) atomicAdd(&ncnt[packed[e] >> 16], 1);
    __syncthreads();
    s[t] = ncnt[t];
    __syncthreads();
    for (int off = 1; off < 256; off <<= 1) {
        int v = (t >= off) ? s[t - off] : 0;
        __syncthreads();
        s[t] += v;
        __syncthreads();
    }
    int excl = t ? s[t - 1] : 0;
    if (t < nInB) {
        rowstart[node0 + t] = beg + excl;
        dinv[node0 + t] = rsqrtf((float)ncnt[t] + 1.0f);
    }
    ncur[t] = beg + excl;
    __syncthreads();
    for (int e = beg + t; e < end; e += 256) {
        unsigned p = packed[e];
        int pos = atomicAdd(&ncur[p >> 16], 1);
        col[pos] = (int)(p & 0xFFFFu);
    }
    if (b == 0 && t == 0) rowstart[N] = E;
}

// ---------------- CSR gather ------------------------------------------------
template <int F>
__global__ __launch_bounds__(256) void gather_kernel(const int* __restrict__ rowstart,
                                                     const int* __restrict__ col,
                                                     const float* __restrict__ dinv,
                                                     const float* __restrict__ hws,
                                                     const float* __restrict__ bias,
                                                     float* __restrict__ agg, int N) {
    const int wave = threadIdx.x >> 6;
    const int lane = threadIdx.x & 63;
    const int d = blockIdx.x * 4 + wave;
    if (d >= N) return;
    const int beg = rowstart[d], end = rowstart[d + 1];
    const float dd = dinv[d];
    if (F == 128) {
        float2 acc = ((const float2*)(hws + (size_t)d * 128))[lane];
        for (int e0 = beg; e0 < end; e0 += 64) {
            int nid = (e0 + lane < end) ? col[e0 + lane] : 0;
            int cnt = min(64, end - e0);
            for (int j = 0; j < cnt; ++j) {
                int s = __shfl(nid, j);
                float2 v = ((const float2*)(hws + (size_t)s * 128))[lane];
                acc.x += v.x;
                acc.y += v.y;
            }
        }
        float2 b = ((const float2*)bias)[lane];
        acc.x = fmaxf(acc.x * dd + b.x, 0.f);
        acc.y = fmaxf(acc.y * dd + b.y, 0.f);
        ((float2*)(agg + (size_t)d * 128))[lane] = acc;
    } else {
        float acc = hws[(size_t)d * 64 + lane];
        for (int e0 = beg; e0 < end; e0 += 64) {
            int nid = (e0 + lane < end) ? col[e0 + lane] : 0;
            int cnt = min(64, end - e0);
            for (int j = 0; j < cnt; ++j) {
                int s = __shfl(nid, j);
                acc += hws[(size_t)s * 64 + lane];
            }
        }
        acc = fmaxf(acc * dd + bias[lane], 0.f);
        agg[(size_t)d * 64 + lane] = acc;
    }
}

// ---------------- edge decode -----------------------------------------------
__global__ __launch_bounds__(256) void decode_kernel(const float* __restrict__ emb1,
                                                     const int* __restrict__ eli,
                                                     const float* __restrict__ Wpost,
                                                     const float* __restrict__ bpost,
                                                     float* __restrict__ pred, int L) {
    const int wave = threadIdx.x >> 6;
    const int lane = threadIdx.x & 63;
    const int l = blockIdx.x * 4 + wave;
    if (l >= L) return;
    int s = eli[l];
    int d = eli[L + l];
    float w = Wpost[lane * 2] + Wpost[lane * 2 + 1];
    float p = emb1[(size_t)s * 64 + lane] * emb1[(size_t)d * 64 + lane] * w;
#pragma unroll
    for (int off = 32; off; off >>= 1) p += __shfl_down(p, off);
    if (lane == 0) pred[l] = p + bpost[0] + bpost[1];
}

// ---------------------------------------------------------------------------
extern "C" void kernel_launch(void* const* d_in, const int* in_sizes, int n_in,
                              void* d_out, int out_size, void* d_ws, size_t ws_size,
                              hipStream_t stream) {
    const float* x     = (const float*)d_in[0];
    const float* prev0 = (const float*)d_in[1];
    const float* prev1 = (const float*)d_in[2];
    const float* Wpre1 = (const float*)d_in[3];
    const float* bpre1 = (const float*)d_in[4];
    const float* Wpre2 = (const float*)d_in[5];
    const float* bpre2 = (const float*)d_in[6];
    const float* Wc1   = (const float*)d_in[7];
    const float* bc1   = (const float*)d_in[8];
    const float* Wc2   = (const float*)d_in[9];
    const float* bc2   = (const float*)d_in[10];
    const float* Wm1   = (const float*)d_in[11];
    const float* bm1   = (const float*)d_in[12];
    const float* Wm2   = (const float*)d_in[13];
    const float* bm2   = (const float*)d_in[14];
    const float* Wpost = (const float*)d_in[15];
    const float* bpost = (const float*)d_in[16];
    const int* edge_index = (const int*)d_in[17];
    const int* eli        = (const int*)d_in[18];

    const int N = in_sizes[0] / 256;   // 50000  (must be <= 65536 for packing)
    const int E = in_sizes[17] / 2;    // 1.6M
    const int L = in_sizes[18] / 2;    // 200K
    const int NB = (N + 255) >> BSHIFT;

    const int* src = edge_index;
    const int* dst = edge_index + E;

    float* out  = (float*)d_out;
    float* pred = out;                        // [L]
    float* emb0 = out + L;                    // [N,128]
    float* emb1 = out + L + (size_t)N * 128;  // [N,64]

    // ---- workspace layout (float slots; peak ~294N = 59 MB) ----
    // [0,128N)    : h1h (G1->G2) | hws1 (G3->gather1) | hws2[0,64N)+agg2[64N,128N)
    // [128N,256N) : packed[E] (build only) | h2 (G2->G3) | agg1 (gather1->G5)
    // [256N, ...) : col[E], rowstart[N+1], dinv[N], weights, bucket arrays
    // h1l lives in d_out's emb0 region (dead until G5): 128N floats = 256N ushorts.
    float* ws = (float*)d_ws;
    ushort_t* h1h = (ushort_t*)ws;                    // [N,256] ushorts
    ushort_t* h1l = (ushort_t*)emb0;                  // [N,256] ushorts (d_out scratch)
    float* hws1 = ws;                                 // [N,128]
    float* hws2 = ws;                                 // [N,64]
    float* agg2 = ws + (size_t)64 * N;                // [N,64]
    float* h2   = ws + (size_t)128 * N;               // [N,128]
    float* agg1 = ws + (size_t)128 * N;               // [N,128]
    unsigned* packed = (unsigned*)(ws + (size_t)128 * N);  // [E] (build phase only)

    size_t o = (size_t)256 * N;
    int* col = (int*)(ws + o);            o += ((size_t)E + 3) & ~(size_t)3;
    int* rowstart = (int*)(ws + o);       o += ((size_t)N + 4) & ~(size_t)3;
    float* dinv = ws + o;                 o += ((size_t)N + 3) & ~(size_t)3;
    int* bbase = (int*)(ws + o);          o += 260;
    int* bcursor = (int*)(ws + o);        o += 260;
    int* bcount = (int*)(ws + o);         o += 260;
    ushort_t* wb = (ushort_t*)(ws + o);   // 327680 ushorts (16B-aligned)

    // weight hi/lo offsets (ushorts) within wb
    ushort_t* wpre1h = wb + 0;       ushort_t* wpre1l = wb + 65536;
    ushort_t* wpre2h = wb + 131072;  ushort_t* wpre2l = wb + 163840;
    ushort_t* wc1h   = wb + 196608;  ushort_t* wc1l   = wb + 212992;
    ushort_t* wm1h   = wb + 229376;  ushort_t* wm1l   = wb + 262144;
    ushort_t* wc2h   = wb + 294912;  ushort_t* wc2l   = wb + 303104;
    ushort_t* wm2h   = wb + 311296;  ushort_t* wm2l   = wb + 319488;

    // 0) bucketed CSR build + dinv (replaces hist/scan/fill + degf/dinv)
    hipMemsetAsync(bcount, 0, (size_t)NB * sizeof(int), stream);
    bcount_kernel<<<1024, 256, 0, stream>>>(dst, bcount, E, NB);
    bscan_kernel<<<1, 256, 0, stream>>>(bcount, bbase, bcursor, NB, E);
    bpart_kernel<<<(E + 8191) / 8192, 256, 0, stream>>>(src, dst, bcursor, packed, E, NB);
    bbuild_kernel<<<NB, 256, 0, stream>>>(bbase, packed, col, rowstart, dinv, N, E);

    // 0b) weights: transpose + hi/lo split
    WAll wa;
    wa.d[0] = {Wpre1, wpre1h, wpre1l, 256, 256};
    wa.d[1] = {Wpre2, wpre2h, wpre2l, 256, 128};
    wa.d[2] = {Wc1,   wc1h,   wc1l,   128, 128};
    wa.d[3] = {Wm1,   wm1h,   wm1l,   256, 128};
    wa.d[4] = {Wc2,   wc2h,   wc2l,   128, 64};
    wa.d[5] = {Wm2,   wm2h,   wm2l,   128, 64};
    wtcvt_kernel<<<dim3(256, 6), 256, 0, stream>>>(wa);

    const int gy = (N + 127) / 128;   // 391

    // 1) h1 = relu(x@Wpre1+b) -> hi/lo bf16            [N,256]
    gemm_mfma<4, true, false, false, false, true><<<dim3(2, gy), 256, 0, stream>>>(
        x, nullptr, nullptr, 256, nullptr, 0, wpre1h, wpre1l, bpre1, nullptr,
        nullptr, h1h, h1l, N, 256);
    // 2) h2 = relu(h1@Wpre2+b)                         [N,128]  (packed dead)
    gemm_mfma<4, true, false, false, true, false><<<dim3(1, gy), 256, 0, stream>>>(
        nullptr, h1h, h1l, 256, nullptr, 0, wpre2h, wpre2l, bpre2, nullptr,
        h2, nullptr, nullptr, N, 128);
    // 3) hws1 = (h2@Wc1)*dinv[row]                     [N,128]  (h1 dead)
    gemm_mfma<4, false, true, false, false, false><<<dim3(1, gy), 256, 0, stream>>>(
        h2, nullptr, nullptr, 128, nullptr, 0, wc1h, wc1l, nullptr, dinv,
        hws1, nullptr, nullptr, N, 128);
    // 4) agg1 = relu(dinv*(hws1[d]+sum hws1[s])+bc1)   (h2 dead)
    gather_kernel<128><<<(N + 3) / 4, 256, 0, stream>>>(rowstart, col, dinv, hws1, bc1, agg1, N);
    // 5) emb0 = [agg1,prev0]@Wm1+bm1  (dual-source concat GEMM)
    gemm_mfma<4, false, false, true, false, false><<<dim3(1, gy), 256, 0, stream>>>(
        agg1, nullptr, nullptr, 128, prev0, 128, wm1h, wm1l, bm1, nullptr,
        emb0, nullptr, nullptr, N, 128);
    // 6) hws2 = (emb0@Wc2)*dinv[row]                   [N,64]  (hws1 dead)
    gemm_mfma<2, false, true, false, false, false><<<dim3(1, gy), 256, 0, stream>>>(
        emb0, nullptr, nullptr, 128, nullptr, 0, wc2h, wc2l, nullptr, dinv,
        hws2, nullptr, nullptr, N, 64);
    // 7) agg2 = relu(dinv*(hws2[d]+sum hws2[s])+bc2)
    gather_kernel<64><<<(N + 3) / 4, 256, 0, stream>>>(rowstart, col, dinv, hws2, bc2, agg2, N);
    // 8) emb1 = [agg2,prev1]@Wm2+bm2
    gemm_mfma<2, false, false, true, false, false><<<dim3(1, gy), 256, 0, stream>>>(
        agg2, nullptr, nullptr, 64, prev1, 64, wm2h, wm2l, bm2, nullptr,
        emb1, nullptr, nullptr, N, 64);
    // 9) decode
    decode_kernel<<<(L + 3) / 4, 256, 0, stream>>>(emb1, eli, Wpost, bpost, pred, L);
}

// Round 6
// 420.019 us; speedup vs baseline: 5.4347x; 1.2872x over previous
//
#include <hip/hip_runtime.h>
#include <hip/hip_bf16.h>

// ---------------------------------------------------------------------------
// ROLAND-style GNN forward. Round 5: bf16 gather operand (halves random-read
// bytes) + 8-deep ILP in the CSR gather inner loop.
// GEMMs: bf16 MFMA hi/lo split-precision (3-pass). Bucketed CSR build.
// ---------------------------------------------------------------------------

typedef unsigned short ushort_t;
typedef __attribute__((ext_vector_type(8))) short s8v;   // 8 bf16 (4 VGPRs)
typedef __attribute__((ext_vector_type(4))) float f4;    // MFMA accumulator

#define BSHIFT 8                       // nodes per bucket = 256 (N<=65536)

// split fp32 into two bf16 (RNE): v ~= hi + lo
__device__ __forceinline__ void bsplit(float v, ushort_t& hi, ushort_t& lo) {
    unsigned u = __float_as_uint(v);
    unsigned rh = u + 0x7FFFu + ((u >> 16) & 1u);
    hi = (ushort_t)(rh >> 16);
    float fh = __uint_as_float((unsigned)hi << 16);
    float d = v - fh;
    unsigned u2 = __float_as_uint(d);
    unsigned rl = u2 + 0x7FFFu + ((u2 >> 16) & 1u);
    lo = (ushort_t)(rl >> 16);
}

__device__ __forceinline__ ushort_t f2bf(float v) {
    unsigned u = __float_as_uint(v);
    return (ushort_t)((u + 0x7FFFu + ((u >> 16) & 1u)) >> 16);
}

// ---------------- MFMA GEMM -------------------------------------------------
// C[M,Nout] = epilogue( A[M,K1] (++ A2[M,K2]) @ W[K,Nout] )
// Wth/Wtl: [Nout][KW] bf16 (transposed+split). A staged 128x64 fp32->hi/lo
// bf16 in LDS, chunk-XOR swizzle. 256 thr = 4 waves (2x2); BM=128, BN=NT*32.
// OUTMODE: 0 = fp32, 1 = hi/lo bf16 pair, 2 = single bf16 (RNE).
template <int NT, bool RELU, bool SCALE, bool DUAL, bool AHILO, int OUTMODE>
__global__ __launch_bounds__(256) void gemm_mfma(
    const float* __restrict__ A1f, const ushort_t* __restrict__ A1h,
    const ushort_t* __restrict__ A1l, int K1,
    const float* __restrict__ A2f, int K2,
    const ushort_t* __restrict__ Wth, const ushort_t* __restrict__ Wtl,
    const float* __restrict__ bias, const float* __restrict__ rowscale,
    float* __restrict__ Cf, ushort_t* __restrict__ Ch, ushort_t* __restrict__ Cl,
    int M, int Nout)
{
    __shared__ ushort_t Ah[128 * 64];
    __shared__ ushort_t Al[128 * 64];
    const int tid  = threadIdx.x;
    const int lane = tid & 63;
    const int w    = tid >> 6;
    const int wr   = w >> 1, wc = w & 1;
    const int bm   = blockIdx.y * 128;
    const int bn   = blockIdx.x * (NT * 32);
    const int KW   = K1 + (DUAL ? K2 : 0);

    f4 acc[4][NT];
    const f4 zero = {0.f, 0.f, 0.f, 0.f};
#pragma unroll
    for (int mi = 0; mi < 4; ++mi)
#pragma unroll
        for (int ni = 0; ni < NT; ++ni) acc[mi][ni] = zero;

    const int sr = tid >> 1;                 // staging row 0..127
    const int sh = tid & 1;                  // staging half
    const int gr = min(bm + sr, M - 1);      // clamped global row

    for (int kt = 0; kt < KW; kt += 64) {
        // ---- stage A tile (128x64) -> hi/lo bf16 LDS, swizzled chunks ----
        {
            const bool ph2 = DUAL && (kt >= K1);
            const float* Af = ph2 ? A2f : A1f;
            const int kb = ph2 ? (kt - K1) : kt;
            const int Ks = ph2 ? K2 : K1;
#pragma unroll
            for (int j = 0; j < 4; ++j) {
                const int c = sh * 4 + j;          // logical 8-elem chunk
                const int p = c ^ (sr & 7);        // physical chunk (swizzle)
                ushort_t hb[8], lb[8];
                if (AHILO && !ph2) {
                    *(s8v*)hb = *(const s8v*)&A1h[(size_t)gr * K1 + kb + c * 8];
                    *(s8v*)lb = *(const s8v*)&A1l[(size_t)gr * K1 + kb + c * 8];
                } else {
                    const float* srcp = &Af[(size_t)gr * Ks + kb + c * 8];
                    f4 v0 = *(const f4*)srcp;
                    f4 v1 = *(const f4*)(srcp + 4);
                    bsplit(v0.x, hb[0], lb[0]); bsplit(v0.y, hb[1], lb[1]);
                    bsplit(v0.z, hb[2], lb[2]); bsplit(v0.w, hb[3], lb[3]);
                    bsplit(v1.x, hb[4], lb[4]); bsplit(v1.y, hb[5], lb[5]);
                    bsplit(v1.z, hb[6], lb[6]); bsplit(v1.w, hb[7], lb[7]);
                }
                *(s8v*)&Ah[sr * 64 + p * 8] = *(const s8v*)hb;
                *(s8v*)&Al[sr * 64 + p * 8] = *(const s8v*)lb;
            }
        }
        __syncthreads();
        // ---- compute: 2 k-subtiles of 32 ----
#pragma unroll
        for (int ks = 0; ks < 2; ++ks) {
            s8v bh[NT], bl[NT];
#pragma unroll
            for (int ni = 0; ni < NT; ++ni) {
                const int n = bn + wc * (NT * 16) + ni * 16 + (lane & 15);
                const size_t off = (size_t)n * KW + kt + ks * 32 + (lane >> 4) * 8;
                bh[ni] = *(const s8v*)&Wth[off];
                bl[ni] = *(const s8v*)&Wtl[off];
            }
#pragma unroll
            for (int mi = 0; mi < 4; ++mi) {
                const int row = wr * 64 + mi * 16 + (lane & 15);
                const int c = ks * 4 + (lane >> 4);
                const int p = c ^ (row & 7);
                const s8v ah = *(const s8v*)&Ah[row * 64 + p * 8];
                const s8v al = *(const s8v*)&Al[row * 64 + p * 8];
#pragma unroll
                for (int ni = 0; ni < NT; ++ni) {
                    acc[mi][ni] = __builtin_amdgcn_mfma_f32_16x16x32_bf16(ah, bh[ni], acc[mi][ni], 0, 0, 0);
                    acc[mi][ni] = __builtin_amdgcn_mfma_f32_16x16x32_bf16(ah, bl[ni], acc[mi][ni], 0, 0, 0);
                    acc[mi][ni] = __builtin_amdgcn_mfma_f32_16x16x32_bf16(al, bh[ni], acc[mi][ni], 0, 0, 0);
                }
            }
        }
        __syncthreads();
    }
    // ---- epilogue: C/D layout col=lane&15, row=(lane>>4)*4+reg ----
#pragma unroll
    for (int mi = 0; mi < 4; ++mi) {
#pragma unroll
        for (int reg = 0; reg < 4; ++reg) {
            const int row = bm + wr * 64 + mi * 16 + (lane >> 4) * 4 + reg;
            if (row >= M) continue;
            const float rs = SCALE ? rowscale[row] : 1.f;
#pragma unroll
            for (int ni = 0; ni < NT; ++ni) {
                const int col = bn + wc * (NT * 16) + ni * 16 + (lane & 15);
                float v = acc[mi][ni][reg];
                if (SCALE) v *= rs;
                if (bias) v += bias[col];
                if (RELU) v = fmaxf(v, 0.f);
                if constexpr (OUTMODE == 1) {
                    ushort_t h, l;
                    bsplit(v, h, l);
                    Ch[(size_t)row * Nout + col] = h;
                    Cl[(size_t)row * Nout + col] = l;
                } else if constexpr (OUTMODE == 2) {
                    Ch[(size_t)row * Nout + col] = f2bf(v);
                } else {
                    Cf[(size_t)row * Nout + col] = v;
                }
            }
        }
    }
}

// ---------------- weight transpose + split ---------------------------------
struct WDesc { const float* W; ushort_t* h; ushort_t* l; int K; int No; };
struct WAll { WDesc d[6]; };

__global__ void wtcvt_kernel(WAll wa) {
    WDesc d = wa.d[blockIdx.y];
    int e = blockIdx.x * blockDim.x + threadIdx.x;
    if (e >= d.K * d.No) return;
    int k = e / d.No, n = e - k * d.No;
    ushort_t h, l;
    bsplit(d.W[e], h, l);
    d.h[(size_t)n * d.K + k] = h;
    d.l[(size_t)n * d.K + k] = l;
}

// ---------------- bucketed CSR build ----------------------------------------
__global__ __launch_bounds__(256) void bcount_kernel(const int* __restrict__ dst,
                                                     int* __restrict__ bcount, int E, int NB) {
    __shared__ int cnt[256];
    const int t = threadIdx.x;
    if (t < NB) cnt[t] = 0;
    __syncthreads();
    for (int e = blockIdx.x * 256 + t; e < E; e += gridDim.x * 256)
        atomicAdd(&cnt[dst[e] >> BSHIFT], 1);
    __syncthreads();
    if (t < NB && cnt[t]) atomicAdd(&bcount[t], cnt[t]);
}

__global__ __launch_bounds__(256) void bscan_kernel(const int* __restrict__ bcount,
                                                    int* __restrict__ bbase,
                                                    int* __restrict__ bcursor, int NB, int E) {
    __shared__ int s[256];
    const int t = threadIdx.x;
    s[t] = (t < NB) ? bcount[t] : 0;
    __syncthreads();
    for (int off = 1; off < 256; off <<= 1) {
        int v = (t >= off) ? s[t - off] : 0;
        __syncthreads();
        s[t] += v;
        __syncthreads();
    }
    int excl = t ? s[t - 1] : 0;
    if (t < NB) { bbase[t] = excl; bcursor[t] = excl; }
    if (t == 0) bbase[NB] = E;
}

__global__ __launch_bounds__(256) void bpart_kernel(const int* __restrict__ src,
                                                    const int* __restrict__ dst,
                                                    int* __restrict__ bcursor,
                                                    unsigned* __restrict__ packed, int E, int NB) {
    __shared__ int cnt[256];
    __shared__ int cur[256];
    const int t = threadIdx.x;
    const int beg = blockIdx.x * 8192;
    const int end = min(beg + 8192, E);
    if (t < NB) cnt[t] = 0;
    __syncthreads();
    for (int e = beg + t; e < end; e += 256) atomicAdd(&cnt[dst[e] >> BSHIFT], 1);
    __syncthreads();
    if (t < NB && cnt[t]) cur[t] = atomicAdd(&bcursor[t], cnt[t]);
    __syncthreads();
    for (int e = beg + t; e < end; e += 256) {
        int d = dst[e];
        int b = d >> BSHIFT;
        int pos = atomicAdd(&cur[b], 1);
        packed[pos] = (unsigned)src[e] | ((unsigned)(d & ((1 << BSHIFT) - 1)) << 16);
    }
}

__global__ __launch_bounds__(256) void bbuild_kernel(const int* __restrict__ bbase,
                                                     const unsigned* __restrict__ packed,
                                                     int* __restrict__ col,
                                                     int* __restrict__ rowstart,
                                                     float* __restrict__ dinv, int N, int E) {
    __shared__ int ncnt[256];
    __shared__ int s[256];
    __shared__ int ncur[256];
    const int b = blockIdx.x;
    const int t = threadIdx.x;
    const int beg = bbase[b], end = bbase[b + 1];
    const int node0 = b << BSHIFT;
    const int nInB = min(256, N - node0);
    ncnt[t] = 0;
    __syncthreads();
    for (int e = beg + t; e < end; e += 256) atomicAdd(&ncnt[packed[e] >> 16], 1);
    __syncthreads();
    s[t] = ncnt[t];
    __syncthreads();
    for (int off = 1; off < 256; off <<= 1) {
        int v = (t >= off) ? s[t - off] : 0;
        __syncthreads();
        s[t] += v;
        __syncthreads();
    }
    int excl = t ? s[t - 1] : 0;
    if (t < nInB) {
        rowstart[node0 + t] = beg + excl;
        dinv[node0 + t] = rsqrtf((float)ncnt[t] + 1.0f);
    }
    ncur[t] = beg + excl;
    __syncthreads();
    for (int e = beg + t; e < end; e += 256) {
        unsigned p = packed[e];
        int pos = atomicAdd(&ncur[p >> 16], 1);
        col[pos] = (int)(p & 0xFFFFu);
    }
    if (b == 0 && t == 0) rowstart[N] = E;
}

// ---------------- CSR gather (bf16 operand, 8-deep ILP) ---------------------
// agg[d,:] = relu(dinv[d]*(hws[d,:] + sum_s hws[s,:]) + bias)
template <int F>
__global__ __launch_bounds__(256) void gather_bf_kernel(const int* __restrict__ rowstart,
                                                        const int* __restrict__ col,
                                                        const float* __restrict__ dinv,
                                                        const ushort_t* __restrict__ hws,
                                                        const float* __restrict__ bias,
                                                        float* __restrict__ agg, int N) {
    const int wave = threadIdx.x >> 6;
    const int lane = threadIdx.x & 63;
    const int d = blockIdx.x * 4 + wave;
    if (d >= N) return;
    const int beg = rowstart[d], end = rowstart[d + 1];
    const float dd = dinv[d];
    if (F == 128) {
        const unsigned* base = (const unsigned*)hws;   // 2 bf16 per uint; row = 64 uints
        unsigned sv = base[(size_t)d * 64 + lane];
        float ax = __uint_as_float(sv << 16);
        float ay = __uint_as_float(sv & 0xFFFF0000u);
        for (int e0 = beg; e0 < end; e0 += 64) {
            int nid = (e0 + lane < end) ? col[e0 + lane] : 0;
            int cnt = min(64, end - e0);
            int j = 0;
            for (; j + 8 <= cnt; j += 8) {
                unsigned u[8];
#pragma unroll
                for (int q = 0; q < 8; ++q) {
                    int s = __shfl(nid, j + q);
                    u[q] = base[(size_t)s * 64 + lane];
                }
#pragma unroll
                for (int q = 0; q < 8; ++q) {
                    ax += __uint_as_float(u[q] << 16);
                    ay += __uint_as_float(u[q] & 0xFFFF0000u);
                }
            }
            for (; j < cnt; ++j) {
                int s = __shfl(nid, j);
                unsigned uu = base[(size_t)s * 64 + lane];
                ax += __uint_as_float(uu << 16);
                ay += __uint_as_float(uu & 0xFFFF0000u);
            }
        }
        float2 b = ((const float2*)bias)[lane];
        float2 r;
        r.x = fmaxf(ax * dd + b.x, 0.f);
        r.y = fmaxf(ay * dd + b.y, 0.f);
        ((float2*)(agg + (size_t)d * 128))[lane] = r;
    } else {  // F == 64: one bf16 per lane
        float acc = __uint_as_float((unsigned)hws[(size_t)d * 64 + lane] << 16);
        for (int e0 = beg; e0 < end; e0 += 64) {
            int nid = (e0 + lane < end) ? col[e0 + lane] : 0;
            int cnt = min(64, end - e0);
            int j = 0;
            for (; j + 8 <= cnt; j += 8) {
                ushort_t u[8];
#pragma unroll
                for (int q = 0; q < 8; ++q) {
                    int s = __shfl(nid, j + q);
                    u[q] = hws[(size_t)s * 64 + lane];
                }
#pragma unroll
                for (int q = 0; q < 8; ++q) acc += __uint_as_float((unsigned)u[q] << 16);
            }
            for (; j < cnt; ++j) {
                int s = __shfl(nid, j);
                acc += __uint_as_float((unsigned)hws[(size_t)s * 64 + lane] << 16);
            }
        }
        acc = fmaxf(acc * dd + bias[lane], 0.f);
        agg[(size_t)d * 64 + lane] = acc;
    }
}

// ---------------- edge decode -----------------------------------------------
__global__ __launch_bounds__(256) void decode_kernel(const float* __restrict__ emb1,
                                                     const int* __restrict__ eli,
                                                     const float* __restrict__ Wpost,
                                                     const float* __restrict__ bpost,
                                                     float* __restrict__ pred, int L) {
    const int wave = threadIdx.x >> 6;
    const int lane = threadIdx.x & 63;
    const int l = blockIdx.x * 4 + wave;
    if (l >= L) return;
    int s = eli[l];
    int d = eli[L + l];
    float w = Wpost[lane * 2] + Wpost[lane * 2 + 1];
    float p = emb1[(size_t)s * 64 + lane] * emb1[(size_t)d * 64 + lane] * w;
#pragma unroll
    for (int off = 32; off; off >>= 1) p += __shfl_down(p, off);
    if (lane == 0) pred[l] = p + bpost[0] + bpost[1];
}

// ---------------------------------------------------------------------------
extern "C" void kernel_launch(void* const* d_in, const int* in_sizes, int n_in,
                              void* d_out, int out_size, void* d_ws, size_t ws_size,
                              hipStream_t stream) {
    const float* x     = (const float*)d_in[0];
    const float* prev0 = (const float*)d_in[1];
    const float* prev1 = (const float*)d_in[2];
    const float* Wpre1 = (const float*)d_in[3];
    const float* bpre1 = (const float*)d_in[4];
    const float* Wpre2 = (const float*)d_in[5];
    const float* bpre2 = (const float*)d_in[6];
    const float* Wc1   = (const float*)d_in[7];
    const float* bc1   = (const float*)d_in[8];
    const float* Wc2   = (const float*)d_in[9];
    const float* bc2   = (const float*)d_in[10];
    const float* Wm1   = (const float*)d_in[11];
    const float* bm1   = (const float*)d_in[12];
    const float* Wm2   = (const float*)d_in[13];
    const float* bm2   = (const float*)d_in[14];
    const float* Wpost = (const float*)d_in[15];
    const float* bpost = (const float*)d_in[16];
    const int* edge_index = (const int*)d_in[17];
    const int* eli        = (const int*)d_in[18];

    const int N = in_sizes[0] / 256;   // 50000  (must be <= 65536 for packing)
    const int E = in_sizes[17] / 2;    // 1.6M
    const int L = in_sizes[18] / 2;    // 200K
    const int NB = (N + 255) >> BSHIFT;

    const int* src = edge_index;
    const int* dst = edge_index + E;

    float* out  = (float*)d_out;
    float* pred = out;                        // [L]
    float* emb0 = out + L;                    // [N,128]
    float* emb1 = out + L + (size_t)N * 128;  // [N,64]

    // ---- workspace layout (float slots; peak ~294N = 59 MB) ----
    // [0,128N)    : h1h (G1->G2) | hws1_bf [N,128]us (G3->gather1) | hws2_bf/agg2
    // [128N,256N) : packed[E] (build only) | h2 (G2->G3) | agg1 (gather1->G5)
    // [256N, ...) : col[E], rowstart[N+1], dinv[N], bucket arrays, weights
    // h1l lives in d_out's emb0 region (dead until G5): 128N floats = 256N ushorts.
    float* ws = (float*)d_ws;
    ushort_t* h1h = (ushort_t*)ws;                    // [N,256] ushorts
    ushort_t* h1l = (ushort_t*)emb0;                  // [N,256] ushorts (d_out scratch)
    ushort_t* hws1b = (ushort_t*)ws;                  // [N,128] ushorts
    ushort_t* hws2b = (ushort_t*)ws;                  // [N,64] ushorts
    float* agg2 = ws + (size_t)64 * N;                // [N,64]
    float* h2   = ws + (size_t)128 * N;               // [N,128]
    float* agg1 = ws + (size_t)128 * N;               // [N,128]
    unsigned* packed = (unsigned*)(ws + (size_t)128 * N);  // [E] (build phase only)

    size_t o = (size_t)256 * N;
    int* col = (int*)(ws + o);            o += ((size_t)E + 3) & ~(size_t)3;
    int* rowstart = (int*)(ws + o);       o += ((size_t)N + 4) & ~(size_t)3;
    float* dinv = ws + o;                 o += ((size_t)N + 3) & ~(size_t)3;
    int* bbase = (int*)(ws + o);          o += 260;
    int* bcursor = (int*)(ws + o);        o += 260;
    int* bcount = (int*)(ws + o);         o += 260;
    ushort_t* wb = (ushort_t*)(ws + o);   // 327680 ushorts (16B-aligned)

    // weight hi/lo offsets (ushorts) within wb
    ushort_t* wpre1h = wb + 0;       ushort_t* wpre1l = wb + 65536;
    ushort_t* wpre2h = wb + 131072;  ushort_t* wpre2l = wb + 163840;
    ushort_t* wc1h   = wb + 196608;  ushort_t* wc1l   = wb + 212992;
    ushort_t* wm1h   = wb + 229376;  ushort_t* wm1l   = wb + 262144;
    ushort_t* wc2h   = wb + 294912;  ushort_t* wc2l   = wb + 303104;
    ushort_t* wm2h   = wb + 311296;  ushort_t* wm2l   = wb + 319488;

    // 0) bucketed CSR build + dinv
    hipMemsetAsync(bcount, 0, (size_t)NB * sizeof(int), stream);
    bcount_kernel<<<1024, 256, 0, stream>>>(dst, bcount, E, NB);
    bscan_kernel<<<1, 256, 0, stream>>>(bcount, bbase, bcursor, NB, E);
    bpart_kernel<<<(E + 8191) / 8192, 256, 0, stream>>>(src, dst, bcursor, packed, E, NB);
    bbuild_kernel<<<NB, 256, 0, stream>>>(bbase, packed, col, rowstart, dinv, N, E);

    // 0b) weights: transpose + hi/lo split
    WAll wa;
    wa.d[0] = {Wpre1, wpre1h, wpre1l, 256, 256};
    wa.d[1] = {Wpre2, wpre2h, wpre2l, 256, 128};
    wa.d[2] = {Wc1,   wc1h,   wc1l,   128, 128};
    wa.d[3] = {Wm1,   wm1h,   wm1l,   256, 128};
    wa.d[4] = {Wc2,   wc2h,   wc2l,   128, 64};
    wa.d[5] = {Wm2,   wm2h,   wm2l,   128, 64};
    wtcvt_kernel<<<dim3(256, 6), 256, 0, stream>>>(wa);

    const int gy = (N + 127) / 128;   // 391

    // 1) h1 = relu(x@Wpre1+b) -> hi/lo bf16            [N,256]
    gemm_mfma<4, true, false, false, false, 1><<<dim3(2, gy), 256, 0, stream>>>(
        x, nullptr, nullptr, 256, nullptr, 0, wpre1h, wpre1l, bpre1, nullptr,
        nullptr, h1h, h1l, N, 256);
    // 2) h2 = relu(h1@Wpre2+b)                         [N,128]  (packed dead)
    gemm_mfma<4, true, false, false, true, 0><<<dim3(1, gy), 256, 0, stream>>>(
        nullptr, h1h, h1l, 256, nullptr, 0, wpre2h, wpre2l, bpre2, nullptr,
        h2, nullptr, nullptr, N, 128);
    // 3) hws1 = bf16((h2@Wc1)*dinv[row])               [N,128]  (h1 dead)
    gemm_mfma<4, false, true, false, false, 2><<<dim3(1, gy), 256, 0, stream>>>(
        h2, nullptr, nullptr, 128, nullptr, 0, wc1h, wc1l, nullptr, dinv,
        nullptr, hws1b, nullptr, N, 128);
    // 4) agg1 = relu(dinv*(hws1[d]+sum hws1[s])+bc1)   (h2 dead)
    gather_bf_kernel<128><<<(N + 3) / 4, 256, 0, stream>>>(rowstart, col, dinv, hws1b, bc1, agg1, N);
    // 5) emb0 = [agg1,prev0]@Wm1+bm1  (dual-source concat GEMM)
    gemm_mfma<4, false, false, true, false, 0><<<dim3(1, gy), 256, 0, stream>>>(
        agg1, nullptr, nullptr, 128, prev0, 128, wm1h, wm1l, bm1, nullptr,
        emb0, nullptr, nullptr, N, 128);
    // 6) hws2 = bf16((emb0@Wc2)*dinv[row])             [N,64]  (hws1 dead)
    gemm_mfma<2, false, true, false, false, 2><<<dim3(1, gy), 256, 0, stream>>>(
        emb0, nullptr, nullptr, 128, nullptr, 0, wc2h, wc2l, nullptr, dinv,
        nullptr, hws2b, nullptr, N, 64);
    // 7) agg2 = relu(dinv*(hws2[d]+sum hws2[s])+bc2)
    gather_bf_kernel<64><<<(N + 3) / 4, 256, 0, stream>>>(rowstart, col, dinv, hws2b, bc2, agg2, N);
    // 8) emb1 = [agg2,prev1]@Wm2+bm2
    gemm_mfma<2, false, false, true, false, 0><<<dim3(1, gy), 256, 0, stream>>>(
        agg2, nullptr, nullptr, 64, prev1, 64, wm2h, wm2l, bm2, nullptr,
        emb1, nullptr, nullptr, N, 64);
    // 9) decode
    decode_kernel<<<(L + 3) / 4, 256, 0, stream>>>(emb1, eli, Wpost, bpost, pred, L);
}

// Round 7
// 404.437 us; speedup vs baseline: 5.6441x; 1.0385x over previous
//
#include <hip/hip_runtime.h>
#include <hip/hip_bf16.h>

// ---------------------------------------------------------------------------
// ROLAND-style GNN forward. Round 6: GEMMs move to 2-pass split precision
// (bf16 activations, hi/lo bf16 weights) + double-buffered pipelined K-loop
// (one barrier per tile, global->reg prefetch overlapped with MFMA).
// Bucketed CSR build; bf16 CSR gather with 8-deep ILP.
// ---------------------------------------------------------------------------

typedef unsigned short ushort_t;
typedef __attribute__((ext_vector_type(8))) short s8v;   // 8 bf16 (4 VGPRs)
typedef __attribute__((ext_vector_type(4))) float f4;    // MFMA accumulator

#define BSHIFT 8                       // nodes per bucket = 256 (N<=65536)

// split fp32 into two bf16 (RNE): v ~= hi + lo  (weights only)
__device__ __forceinline__ void bsplit(float v, ushort_t& hi, ushort_t& lo) {
    unsigned u = __float_as_uint(v);
    unsigned rh = u + 0x7FFFu + ((u >> 16) & 1u);
    hi = (ushort_t)(rh >> 16);
    float fh = __uint_as_float((unsigned)hi << 16);
    float d = v - fh;
    unsigned u2 = __float_as_uint(d);
    unsigned rl = u2 + 0x7FFFu + ((u2 >> 16) & 1u);
    lo = (ushort_t)(rl >> 16);
}

__device__ __forceinline__ ushort_t f2bf(float v) {
    unsigned u = __float_as_uint(v);
    return (ushort_t)((u + 0x7FFFu + ((u >> 16) & 1u)) >> 16);
}

// ---------------- MFMA GEMM (2-pass, double-buffered) -----------------------
// C[M,Nout] = epilogue( A[M,K1] (++ A2[M,K2]) @ W[K,Nout] )
// A quantized to bf16 in LDS (chunk-XOR swizzle); W pre-split hi/lo [Nout][KW].
// acc += Ah*Wh + Ah*Wl per k-subtile. 256 thr = 4 waves (2x2); BM=128.
// OUTMODE: 0 = fp32, 2 = single bf16.  ABF: A1 is pre-quantized bf16 (requires !DUAL).
template <int NT, bool RELU, bool SCALE, bool DUAL, bool ABF, int OUTMODE>
__global__ __launch_bounds__(256) void gemm_mfma(
    const float* __restrict__ A1f, const ushort_t* __restrict__ A1h, int K1,
    const float* __restrict__ A2f, int K2,
    const ushort_t* __restrict__ Wth, const ushort_t* __restrict__ Wtl,
    const float* __restrict__ bias, const float* __restrict__ rowscale,
    float* __restrict__ Cf, ushort_t* __restrict__ Ch,
    int M, int Nout)
{
    __shared__ ushort_t Abuf[2][128 * 64];
    const int tid  = threadIdx.x;
    const int lane = tid & 63;
    const int w    = tid >> 6;
    const int wr   = w >> 1, wc = w & 1;
    const int bm   = blockIdx.y * 128;
    const int bn   = blockIdx.x * (NT * 32);
    const int KW   = K1 + (DUAL ? K2 : 0);
    const int nt   = KW >> 6;

    f4 acc[4][NT];
    const f4 zero = {0.f, 0.f, 0.f, 0.f};
#pragma unroll
    for (int mi = 0; mi < 4; ++mi)
#pragma unroll
        for (int ni = 0; ni < NT; ++ni) acc[mi][ni] = zero;

    const int sr = tid >> 1;                 // staging row 0..127
    const int sh = tid & 1;                  // staging half (chunks 0..3 / 4..7)
    const int gr = min(bm + sr, M - 1);      // clamped global row

    f4  pr[8];    // raw fp32 prefetch (non-ABF)
    s8v pu[4];    // raw bf16 prefetch (ABF)

    auto loadT = [&](int kt) {
        if constexpr (ABF) {
#pragma unroll
            for (int j = 0; j < 4; ++j)
                pu[j] = *(const s8v*)&A1h[(size_t)gr * K1 + kt + (sh * 4 + j) * 8];
        } else {
            const float* Af; int kb, Ks;
            if (DUAL && kt >= K1) { Af = A2f; kb = kt - K1; Ks = K2; }
            else                  { Af = A1f; kb = kt;      Ks = K1; }
#pragma unroll
            for (int j = 0; j < 4; ++j) {
                const float* sp = &Af[(size_t)gr * Ks + kb + (sh * 4 + j) * 8];
                pr[2 * j]     = *(const f4*)sp;
                pr[2 * j + 1] = *(const f4*)(sp + 4);
            }
        }
    };
    auto storeT = [&](ushort_t* buf) {
#pragma unroll
        for (int j = 0; j < 4; ++j) {
            const int c = sh * 4 + j;
            const int p = c ^ (sr & 7);            // bank swizzle
            ushort_t hb[8];
            if constexpr (ABF) {
                *(s8v*)hb = pu[j];
            } else {
                f4 v0 = pr[2 * j], v1 = pr[2 * j + 1];
                hb[0] = f2bf(v0.x); hb[1] = f2bf(v0.y);
                hb[2] = f2bf(v0.z); hb[3] = f2bf(v0.w);
                hb[4] = f2bf(v1.x); hb[5] = f2bf(v1.y);
                hb[6] = f2bf(v1.z); hb[7] = f2bf(v1.w);
            }
            *(s8v*)&buf[sr * 64 + p * 8] = *(const s8v*)hb;
        }
    };

    loadT(0);
    storeT(Abuf[0]);
    __syncthreads();
    int cur = 0;

    for (int t = 0; t < nt; ++t) {
        if (t + 1 < nt) loadT((t + 1) * 64);     // issue next-tile global loads
        const int kt = t * 64;
#pragma unroll
        for (int ks = 0; ks < 2; ++ks) {
            s8v bh[NT], bl[NT];
#pragma unroll
            for (int ni = 0; ni < NT; ++ni) {
                const int n = bn + wc * (NT * 16) + ni * 16 + (lane & 15);
                const size_t off = (size_t)n * KW + kt + ks * 32 + (lane >> 4) * 8;
                bh[ni] = *(const s8v*)&Wth[off];
                bl[ni] = *(const s8v*)&Wtl[off];
            }
#pragma unroll
            for (int mi = 0; mi < 4; ++mi) {
                const int row = wr * 64 + mi * 16 + (lane & 15);
                const int c = ks * 4 + (lane >> 4);
                const int p = c ^ (row & 7);
                const s8v ah = *(const s8v*)&Abuf[cur][row * 64 + p * 8];
#pragma unroll
                for (int ni = 0; ni < NT; ++ni) {
                    acc[mi][ni] = __builtin_amdgcn_mfma_f32_16x16x32_bf16(ah, bh[ni], acc[mi][ni], 0, 0, 0);
                    acc[mi][ni] = __builtin_amdgcn_mfma_f32_16x16x32_bf16(ah, bl[ni], acc[mi][ni], 0, 0, 0);
                }
            }
        }
        if (t + 1 < nt) storeT(Abuf[cur ^ 1]);   // waits on vmcnt here, not before MFMA
        __syncthreads();
        cur ^= 1;
    }

    // ---- epilogue: C/D layout col=lane&15, row=(lane>>4)*4+reg ----
#pragma unroll
    for (int mi = 0; mi < 4; ++mi) {
#pragma unroll
        for (int reg = 0; reg < 4; ++reg) {
            const int row = bm + wr * 64 + mi * 16 + (lane >> 4) * 4 + reg;
            if (row >= M) continue;
            const float rs = SCALE ? rowscale[row] : 1.f;
#pragma unroll
            for (int ni = 0; ni < NT; ++ni) {
                const int col = bn + wc * (NT * 16) + ni * 16 + (lane & 15);
                float v = acc[mi][ni][reg];
                if (SCALE) v *= rs;
                if (bias) v += bias[col];
                if (RELU) v = fmaxf(v, 0.f);
                if constexpr (OUTMODE == 2) {
                    Ch[(size_t)row * Nout + col] = f2bf(v);
                } else {
                    Cf[(size_t)row * Nout + col] = v;
                }
            }
        }
    }
}

// ---------------- weight transpose + split ---------------------------------
struct WDesc { const float* W; ushort_t* h; ushort_t* l; int K; int No; };
struct WAll { WDesc d[6]; };

__global__ void wtcvt_kernel(WAll wa) {
    WDesc d = wa.d[blockIdx.y];
    int e = blockIdx.x * blockDim.x + threadIdx.x;
    if (e >= d.K * d.No) return;
    int k = e / d.No, n = e - k * d.No;
    ushort_t h, l;
    bsplit(d.W[e], h, l);
    d.h[(size_t)n * d.K + k] = h;
    d.l[(size_t)n * d.K + k] = l;
}

// ---------------- bucketed CSR build ----------------------------------------
__global__ __launch_bounds__(256) void bcount_kernel(const int* __restrict__ dst,
                                                     int* __restrict__ bcount, int E, int NB) {
    __shared__ int cnt[256];
    const int t = threadIdx.x;
    if (t < NB) cnt[t] = 0;
    __syncthreads();
    for (int e = blockIdx.x * 256 + t; e < E; e += gridDim.x * 256)
        atomicAdd(&cnt[dst[e] >> BSHIFT], 1);
    __syncthreads();
    if (t < NB && cnt[t]) atomicAdd(&bcount[t], cnt[t]);
}

__global__ __launch_bounds__(256) void bscan_kernel(const int* __restrict__ bcount,
                                                    int* __restrict__ bbase,
                                                    int* __restrict__ bcursor, int NB, int E) {
    __shared__ int s[256];
    const int t = threadIdx.x;
    s[t] = (t < NB) ? bcount[t] : 0;
    __syncthreads();
    for (int off = 1; off < 256; off <<= 1) {
        int v = (t >= off) ? s[t - off] : 0;
        __syncthreads();
        s[t] += v;
        __syncthreads();
    }
    int excl = t ? s[t - 1] : 0;
    if (t < NB) { bbase[t] = excl; bcursor[t] = excl; }
    if (t == 0) bbase[NB] = E;
}

__global__ __launch_bounds__(256) void bpart_kernel(const int* __restrict__ src,
                                                    const int* __restrict__ dst,
                                                    int* __restrict__ bcursor,
                                                    unsigned* __restrict__ packed, int E, int NB) {
    __shared__ int cnt[256];
    __shared__ int cur[256];
    const int t = threadIdx.x;
    const int beg = blockIdx.x * 8192;
    const int end = min(beg + 8192, E);
    if (t < NB) cnt[t] = 0;
    __syncthreads();
    for (int e = beg + t; e < end; e += 256) atomicAdd(&cnt[dst[e] >> BSHIFT], 1);
    __syncthreads();
    if (t < NB && cnt[t]) cur[t] = atomicAdd(&bcursor[t], cnt[t]);
    __syncthreads();
    for (int e = beg + t; e < end; e += 256) {
        int d = dst[e];
        int b = d >> BSHIFT;
        int pos = atomicAdd(&cur[b], 1);
        packed[pos] = (unsigned)src[e] | ((unsigned)(d & ((1 << BSHIFT) - 1)) << 16);
    }
}

__global__ __launch_bounds__(256) void bbuild_kernel(const int* __restrict__ bbase,
                                                     const unsigned* __restrict__ packed,
                                                     int* __restrict__ col,
                                                     int* __restrict__ rowstart,
                                                     float* __restrict__ dinv, int N, int E) {
    __shared__ int ncnt[256];
    __shared__ int s[256];
    __shared__ int ncur[256];
    const int b = blockIdx.x;
    const int t = threadIdx.x;
    const int beg = bbase[b], end = bbase[b + 1];
    const int node0 = b << BSHIFT;
    const int nInB = min(256, N - node0);
    ncnt[t] = 0;
    __syncthreads();
    for (int e = beg + t; e < end; e += 256) atomicAdd(&ncnt[packed[e] >> 16], 1);
    __syncthreads();
    s[t] = ncnt[t];
    __syncthreads();
    for (int off = 1; off < 256; off <<= 1) {
        int v = (t >= off) ? s[t - off] : 0;
        __syncthreads();
        s[t] += v;
        __syncthreads();
    }
    int excl = t ? s[t - 1] : 0;
    if (t < nInB) {
        rowstart[node0 + t] = beg + excl;
        dinv[node0 + t] = rsqrtf((float)ncnt[t] + 1.0f);
    }
    ncur[t] = beg + excl;
    __syncthreads();
    for (int e = beg + t; e < end; e += 256) {
        unsigned p = packed[e];
        int pos = atomicAdd(&ncur[p >> 16], 1);
        col[pos] = (int)(p & 0xFFFFu);
    }
    if (b == 0 && t == 0) rowstart[N] = E;
}

// ---------------- CSR gather (bf16 operand, 8-deep ILP) ---------------------
template <int F>
__global__ __launch_bounds__(256) void gather_bf_kernel(const int* __restrict__ rowstart,
                                                        const int* __restrict__ col,
                                                        const float* __restrict__ dinv,
                                                        const ushort_t* __restrict__ hws,
                                                        const float* __restrict__ bias,
                                                        float* __restrict__ agg, int N) {
    const int wave = threadIdx.x >> 6;
    const int lane = threadIdx.x & 63;
    const int d = blockIdx.x * 4 + wave;
    if (d >= N) return;
    const int beg = rowstart[d], end = rowstart[d + 1];
    const float dd = dinv[d];
    if (F == 128) {
        const unsigned* base = (const unsigned*)hws;   // 2 bf16 per uint; row = 64 uints
        unsigned sv = base[(size_t)d * 64 + lane];
        float ax = __uint_as_float(sv << 16);
        float ay = __uint_as_float(sv & 0xFFFF0000u);
        for (int e0 = beg; e0 < end; e0 += 64) {
            int nid = (e0 + lane < end) ? col[e0 + lane] : 0;
            int cnt = min(64, end - e0);
            int j = 0;
            for (; j + 8 <= cnt; j += 8) {
                unsigned u[8];
#pragma unroll
                for (int q = 0; q < 8; ++q) {
                    int s = __shfl(nid, j + q);
                    u[q] = base[(size_t)s * 64 + lane];
                }
#pragma unroll
                for (int q = 0; q < 8; ++q) {
                    ax += __uint_as_float(u[q] << 16);
                    ay += __uint_as_float(u[q] & 0xFFFF0000u);
                }
            }
            for (; j < cnt; ++j) {
                int s = __shfl(nid, j);
                unsigned uu = base[(size_t)s * 64 + lane];
                ax += __uint_as_float(uu << 16);
                ay += __uint_as_float(uu & 0xFFFF0000u);
            }
        }
        float2 b = ((const float2*)bias)[lane];
        float2 r;
        r.x = fmaxf(ax * dd + b.x, 0.f);
        r.y = fmaxf(ay * dd + b.y, 0.f);
        ((float2*)(agg + (size_t)d * 128))[lane] = r;
    } else {  // F == 64: one bf16 per lane
        float acc = __uint_as_float((unsigned)hws[(size_t)d * 64 + lane] << 16);
        for (int e0 = beg; e0 < end; e0 += 64) {
            int nid = (e0 + lane < end) ? col[e0 + lane] : 0;
            int cnt = min(64, end - e0);
            int j = 0;
            for (; j + 8 <= cnt; j += 8) {
                ushort_t u[8];
#pragma unroll
                for (int q = 0; q < 8; ++q) {
                    int s = __shfl(nid, j + q);
                    u[q] = hws[(size_t)s * 64 + lane];
                }
#pragma unroll
                for (int q = 0; q < 8; ++q) acc += __uint_as_float((unsigned)u[q] << 16);
            }
            for (; j < cnt; ++j) {
                int s = __shfl(nid, j);
                acc += __uint_as_float((unsigned)hws[(size_t)s * 64 + lane] << 16);
            }
        }
        acc = fmaxf(acc * dd + bias[lane], 0.f);
        agg[(size_t)d * 64 + lane] = acc;
    }
}

// ---------------- edge decode -----------------------------------------------
__global__ __launch_bounds__(256) void decode_kernel(const float* __restrict__ emb1,
                                                     const int* __restrict__ eli,
                                                     const float* __restrict__ Wpost,
                                                     const float* __restrict__ bpost,
                                                     float* __restrict__ pred, int L) {
    const int wave = threadIdx.x >> 6;
    const int lane = threadIdx.x & 63;
    const int l = blockIdx.x * 4 + wave;
    if (l >= L) return;
    int s = eli[l];
    int d = eli[L + l];
    float w = Wpost[lane * 2] + Wpost[lane * 2 + 1];
    float p = emb1[(size_t)s * 64 + lane] * emb1[(size_t)d * 64 + lane] * w;
#pragma unroll
    for (int off = 32; off; off >>= 1) p += __shfl_down(p, off);
    if (lane == 0) pred[l] = p + bpost[0] + bpost[1];
}

// ---------------------------------------------------------------------------
extern "C" void kernel_launch(void* const* d_in, const int* in_sizes, int n_in,
                              void* d_out, int out_size, void* d_ws, size_t ws_size,
                              hipStream_t stream) {
    const float* x     = (const float*)d_in[0];
    const float* prev0 = (const float*)d_in[1];
    const float* prev1 = (const float*)d_in[2];
    const float* Wpre1 = (const float*)d_in[3];
    const float* bpre1 = (const float*)d_in[4];
    const float* Wpre2 = (const float*)d_in[5];
    const float* bpre2 = (const float*)d_in[6];
    const float* Wc1   = (const float*)d_in[7];
    const float* bc1   = (const float*)d_in[8];
    const float* Wc2   = (const float*)d_in[9];
    const float* bc2   = (const float*)d_in[10];
    const float* Wm1   = (const float*)d_in[11];
    const float* bm1   = (const float*)d_in[12];
    const float* Wm2   = (const float*)d_in[13];
    const float* bm2   = (const float*)d_in[14];
    const float* Wpost = (const float*)d_in[15];
    const float* bpost = (const float*)d_in[16];
    const int* edge_index = (const int*)d_in[17];
    const int* eli        = (const int*)d_in[18];

    const int N = in_sizes[0] / 256;   // 50000  (must be <= 65536 for packing)
    const int E = in_sizes[17] / 2;    // 1.6M
    const int L = in_sizes[18] / 2;    // 200K
    const int NB = (N + 255) >> BSHIFT;

    const int* src = edge_index;
    const int* dst = edge_index + E;

    float* out  = (float*)d_out;
    float* pred = out;                        // [L]
    float* emb0 = out + L;                    // [N,128]
    float* emb1 = out + L + (size_t)N * 128;  // [N,64]

    // ---- workspace layout (float slots; peak ~256N + tail = 59 MB) ----
    // [0,128N)    : h1h [N,256]us (G1->G2) | hws1b [N,128]us (G3->gather1)
    //               | hws2b [N,64]us [0,32N) + agg2 [N,64]f32 [64N,128N)
    // [128N,256N) : packed[E] (build only) | h2 [N,128]f32 (G2->G3)
    //               | agg1 [N,128]f32 (gather1->G5)
    // [256N, ...) : col[E], rowstart[N+1], dinv[N], bucket arrays, weights
    float* ws = (float*)d_ws;
    ushort_t* h1h   = (ushort_t*)ws;                  // [N,256] ushorts
    ushort_t* hws1b = (ushort_t*)ws;                  // [N,128] ushorts
    ushort_t* hws2b = (ushort_t*)ws;                  // [N,64] ushorts
    float* agg2 = ws + (size_t)64 * N;                // [N,64] f32
    float* h2   = ws + (size_t)128 * N;               // [N,128] f32
    float* agg1 = ws + (size_t)128 * N;               // [N,128] f32
    unsigned* packed = (unsigned*)(ws + (size_t)128 * N);  // [E] (build phase only)

    size_t o = (size_t)256 * N;
    int* col = (int*)(ws + o);            o += ((size_t)E + 3) & ~(size_t)3;
    int* rowstart = (int*)(ws + o);       o += ((size_t)N + 4) & ~(size_t)3;
    float* dinv = ws + o;                 o += ((size_t)N + 3) & ~(size_t)3;
    int* bbase = (int*)(ws + o);          o += 260;
    int* bcursor = (int*)(ws + o);        o += 260;
    int* bcount = (int*)(ws + o);         o += 260;
    ushort_t* wb = (ushort_t*)(ws + o);   // 327680 ushorts (16B-aligned)

    // weight hi/lo offsets (ushorts) within wb
    ushort_t* wpre1h = wb + 0;       ushort_t* wpre1l = wb + 65536;
    ushort_t* wpre2h = wb + 131072;  ushort_t* wpre2l = wb + 163840;
    ushort_t* wc1h   = wb + 196608;  ushort_t* wc1l   = wb + 212992;
    ushort_t* wm1h   = wb + 229376;  ushort_t* wm1l   = wb + 262144;
    ushort_t* wc2h   = wb + 294912;  ushort_t* wc2l   = wb + 303104;
    ushort_t* wm2h   = wb + 311296;  ushort_t* wm2l   = wb + 319488;

    // 0) bucketed CSR build + dinv
    hipMemsetAsync(bcount, 0, (size_t)NB * sizeof(int), stream);
    bcount_kernel<<<1024, 256, 0, stream>>>(dst, bcount, E, NB);
    bscan_kernel<<<1, 256, 0, stream>>>(bcount, bbase, bcursor, NB, E);
    bpart_kernel<<<(E + 8191) / 8192, 256, 0, stream>>>(src, dst, bcursor, packed, E, NB);
    bbuild_kernel<<<NB, 256, 0, stream>>>(bbase, packed, col, rowstart, dinv, N, E);

    // 0b) weights: transpose + hi/lo split
    WAll wa;
    wa.d[0] = {Wpre1, wpre1h, wpre1l, 256, 256};
    wa.d[1] = {Wpre2, wpre2h, wpre2l, 256, 128};
    wa.d[2] = {Wc1,   wc1h,   wc1l,   128, 128};
    wa.d[3] = {Wm1,   wm1h,   wm1l,   256, 128};
    wa.d[4] = {Wc2,   wc2h,   wc2l,   128, 64};
    wa.d[5] = {Wm2,   wm2h,   wm2l,   128, 64};
    wtcvt_kernel<<<dim3(256, 6), 256, 0, stream>>>(wa);

    const int gy = (N + 127) / 128;   // 391

    // 1) h1 = relu(x@Wpre1+b) -> bf16                  [N,256]
    gemm_mfma<4, true, false, false, false, 2><<<dim3(2, gy), 256, 0, stream>>>(
        x, nullptr, 256, nullptr, 0, wpre1h, wpre1l, bpre1, nullptr,
        nullptr, h1h, N, 256);
    // 2) h2 = relu(h1@Wpre2+b)                         [N,128]  (packed dead)
    gemm_mfma<4, true, false, false, true, 0><<<dim3(1, gy), 256, 0, stream>>>(
        nullptr, h1h, 256, nullptr, 0, wpre2h, wpre2l, bpre2, nullptr,
        h2, nullptr, N, 128);
    // 3) hws1 = bf16((h2@Wc1)*dinv[row])               [N,128]  (h1 dead)
    gemm_mfma<4, false, true, false, false, 2><<<dim3(1, gy), 256, 0, stream>>>(
        h2, nullptr, 128, nullptr, 0, wc1h, wc1l, nullptr, dinv,
        nullptr, hws1b, N, 128);
    // 4) agg1 = relu(dinv*(hws1[d]+sum hws1[s])+bc1)   (h2 dead)
    gather_bf_kernel<128><<<(N + 3) / 4, 256, 0, stream>>>(rowstart, col, dinv, hws1b, bc1, agg1, N);
    // 5) emb0 = [agg1,prev0]@Wm1+bm1  (dual-source concat GEMM)
    gemm_mfma<4, false, false, true, false, 0><<<dim3(1, gy), 256, 0, stream>>>(
        agg1, nullptr, 128, prev0, 128, wm1h, wm1l, bm1, nullptr,
        emb0, nullptr, N, 128);
    // 6) hws2 = bf16((emb0@Wc2)*dinv[row])             [N,64]  (hws1 dead)
    gemm_mfma<2, false, true, false, false, 2><<<dim3(1, gy), 256, 0, stream>>>(
        emb0, nullptr, 128, nullptr, 0, wc2h, wc2l, nullptr, dinv,
        nullptr, hws2b, N, 64);
    // 7) agg2 = relu(dinv*(hws2[d]+sum hws2[s])+bc2)
    gather_bf_kernel<64><<<(N + 3) / 4, 256, 0, stream>>>(rowstart, col, dinv, hws2b, bc2, agg2, N);
    // 8) emb1 = [agg2,prev1]@Wm2+bm2
    gemm_mfma<2, false, false, true, false, 0><<<dim3(1, gy), 256, 0, stream>>>(
        agg2, nullptr, 64, prev1, 64, wm2h, wm2l, bm2, nullptr,
        emb1, nullptr, N, 64);
    // 9) decode
    decode_kernel<<<(L + 3) / 4, 256, 0, stream>>>(emb1, eli, Wpost, bpost, pred, L);
}